// Round 13
// baseline (1328.531 us; speedup 1.0000x reference)
//
#include <hip/hip_runtime.h>

// ParallelMemoryModule: mlp1 -> memory-attention -> mlp2 on MI355X.
// R12: split-K=2 for the two K=8192 down-projections (grid 1024 -> 3 blocks/CU
// TLP; fp32 partials alias KVRAW; fused reduce adds bias/residual).
// Everything else = R11 (gemm_s 128^2@3/CU, gemm_w 128x256@2/CU, attn R8).

typedef unsigned short ushort_t;
typedef __attribute__((ext_vector_type(8))) short bf16x8;
typedef __attribute__((ext_vector_type(4))) float f32x4;

#define DEVI __device__ __forceinline__

DEVI ushort_t f2bf(float f) {
  unsigned int u = __builtin_bit_cast(unsigned int, f);
  u += 0x7FFFu + ((u >> 16) & 1u);
  return (ushort_t)(u >> 16);
}
DEVI float bf2f(ushort_t h) {
  unsigned int u = ((unsigned int)h) << 16;
  return __builtin_bit_cast(float, u);
}

DEVI void load_lds16(const void* g, void* l) {
  __builtin_amdgcn_global_load_lds(
      (__attribute__((address_space(1))) void*)(g),
      (__attribute__((address_space(3))) void*)(l), 16, 0, 0);
}

// ---------------------------------------------------------------- mask dtype
__global__ void detect_mask_k(const unsigned int* __restrict__ m, int* __restrict__ flag) {
  unsigned int v = m[threadIdx.x];
  unsigned long long ok = __ballot(v <= 1u);
  if (threadIdx.x == 0) *flag = (ok == ~0ull) ? 1 : 0;
}

// ---------------------------------------------------------------- mask pack
__global__ __launch_bounds__(256)
void mask_pack_k(const void* __restrict__ maskp, const int* __restrict__ mtype,
                 unsigned long long* __restrict__ out, int nwords) {
  const int mint = *mtype;
  const int lane = threadIdx.x & 63;
  const int wglob = blockIdx.x * 4 + (threadIdx.x >> 6);
  const int nw = gridDim.x * 4;
  const unsigned char* m8 = (const unsigned char*)maskp;
  const int* m32 = (const int*)maskp;
  for (int i = wglob; i < nwords; i += nw) {
    const size_t e = (size_t)i * 64 + lane;
    const bool v = mint ? (m32[e] != 0) : (m8[e] != 0);
    unsigned long long bits = __ballot(v);
    if (lane == 0) out[i] = bits;
  }
}

// ---------------------------------------------------------------- transpose W
__global__ __launch_bounds__(256)
void transpose_w(const float* __restrict__ in, ushort_t* __restrict__ out, int K, int N) {
  __shared__ float t[64][65];
  const int tid = threadIdx.x;
  const int tx = tid & 63, ty = tid >> 6;
  const int n0 = blockIdx.x * 64, k0 = blockIdx.y * 64;
#pragma unroll
  for (int i = 0; i < 16; ++i)
    t[ty + i * 4][tx] = in[(size_t)(k0 + ty + i * 4) * N + n0 + tx];
  __syncthreads();
  const int l32 = tid & 31, nr = tid >> 5;
#pragma unroll
  for (int i = 0; i < 8; ++i) {
    const int n = nr + i * 8;
    ushort2 o;
    o.x = f2bf(t[2 * l32][n]);
    o.y = f2bf(t[2 * l32 + 1][n]);
    *(ushort2*)&out[(size_t)(n0 + n) * K + k0 + 2 * l32] = o;
  }
}

// ---------------------------------------------------------------- f32->bf16
__global__ void f32_to_bf16_k(const float* __restrict__ in, ushort_t* __restrict__ out, int n4) {
  int i = blockIdx.x * blockDim.x + threadIdx.x;
  int stride = gridDim.x * blockDim.x;
  for (; i < n4; i += stride) {
    float4 v = ((const float4*)in)[i];
    ushort4 o;
    o.x = f2bf(v.x); o.y = f2bf(v.y); o.z = f2bf(v.z); o.w = f2bf(v.w);
    ((ushort4*)out)[i] = o;
  }
}

// ---------------------------------------------------------------- layernorm
__global__ __launch_bounds__(256)
void ln_kernel(const float* __restrict__ in, const float* __restrict__ gam,
               const float* __restrict__ bet, ushort_t* __restrict__ out) {
  const int row = blockIdx.x;
  const float* p = in + (size_t)row * 2048;
  const int tid = threadIdx.x;
  float4 v0 = ((const float4*)p)[tid * 2];
  float4 v1 = ((const float4*)p)[tid * 2 + 1];
  float s = v0.x + v0.y + v0.z + v0.w + v1.x + v1.y + v1.z + v1.w;
  float q = v0.x * v0.x + v0.y * v0.y + v0.z * v0.z + v0.w * v0.w +
            v1.x * v1.x + v1.y * v1.y + v1.z * v1.z + v1.w * v1.w;
#pragma unroll
  for (int m = 1; m < 64; m <<= 1) { s += __shfl_xor(s, m); q += __shfl_xor(q, m); }
  __shared__ float red[8];
  const int w = tid >> 6;
  if ((tid & 63) == 0) { red[w] = s; red[4 + w] = q; }
  __syncthreads();
  s = red[0] + red[1] + red[2] + red[3];
  q = red[4] + red[5] + red[6] + red[7];
  const float mean = s * (1.f / 2048.f);
  const float var = q * (1.f / 2048.f) - mean * mean;
  const float rs = rsqrtf(var + 1e-5f);
  float4 g0 = ((const float4*)gam)[tid * 2], g1 = ((const float4*)gam)[tid * 2 + 1];
  float4 b0 = ((const float4*)bet)[tid * 2], b1 = ((const float4*)bet)[tid * 2 + 1];
  ushort4 o0, o1;
  o0.x = f2bf((v0.x - mean) * rs * g0.x + b0.x);
  o0.y = f2bf((v0.y - mean) * rs * g0.y + b0.y);
  o0.z = f2bf((v0.z - mean) * rs * g0.z + b0.z);
  o0.w = f2bf((v0.w - mean) * rs * g0.w + b0.w);
  o1.x = f2bf((v1.x - mean) * rs * g1.x + b1.x);
  o1.y = f2bf((v1.y - mean) * rs * g1.y + b1.y);
  o1.z = f2bf((v1.z - mean) * rs * g1.z + b1.z);
  o1.w = f2bf((v1.w - mean) * rs * g1.w + b1.w);
  ushort4* ob = (ushort4*)(out + (size_t)row * 2048);
  ob[tid * 2] = o0;
  ob[tid * 2 + 1] = o1;
}

// ---------------------------------------------------------------- V transpose
__global__ __launch_bounds__(256)
void vtrans_k(const ushort_t* __restrict__ kv, ushort_t* __restrict__ vt) {
  __shared__ ushort_t t[32][33];
  const int tx = threadIdx.x, ty = threadIdx.y;
  const int m0 = blockIdx.x * 32, d0 = blockIdx.y * 32, bh = blockIdx.z;
  const int b = bh >> 4, h = bh & 15;
#pragma unroll
  for (int i = 0; i < 4; ++i)
    t[ty + i * 8][tx] = kv[((size_t)(m0 + ty + i * 8) * 2 + b) * 4096 + h * 256 + 128 + d0 + tx];
  __syncthreads();
#pragma unroll
  for (int i = 0; i < 4; ++i)
    vt[((size_t)bh * 128 + d0 + ty + i * 8) * 4096 + m0 + tx] = t[tx][ty + i * 8];
}

// ---------------------------------------------------------------- GEMM 128^2
// m97-class (PROVEN): 128x128, BK=64, 4 waves, single-buf 32KB, 2-barrier,
// 3 blocks/CU (124 regs/thread: VGPR 60 + AGPR 64).
// EPI: 0 bias+gelu->bf16 ; 2 bias->f32 ; 3 Xres+acc+bias->f32 ;
//      4 l2norm(row over 128 tile cols)*nscale -> bf16
template <int EPI>
__global__ __launch_bounds__(256, 3)
void gemm_s(const ushort_t* __restrict__ A, const ushort_t* __restrict__ Bt,
            const float* __restrict__ bias, const float* __restrict__ Xres,
            void* __restrict__ Out, int N, int K, int GM, float nscale) {
  __shared__ ushort_t lA[128 * 64];
  __shared__ ushort_t lB[128 * 64];

  const int tid = threadIdx.x;
  const int lane = tid & 63;
  const int w = tid >> 6;
  const int l15 = lane & 15, lhi = lane >> 4;
  const int wr = w >> 1, wc = w & 1;

  const int nwg = gridDim.x;
  const int cpx = nwg >> 3;
  const int swz = (blockIdx.x & 7) * cpx + (blockIdx.x >> 3);
  const int tm = swz % GM, tn = swz / GM;

  size_t aSrc[4], bSrc[4];
#pragma unroll
  for (int i = 0; i < 4; ++i) {
    const int ch = i * 256 + tid;
    const int row = ch >> 3;
    const int colb = ((ch & 7) * 16) ^ ((row & 7) << 4);
    aSrc[i] = (size_t)(tm * 128 + row) * K + (colb >> 1);
    bSrc[i] = (size_t)(tn * 128 + row) * K + (colb >> 1);
  }

  f32x4 acc[4][4] = {};

  const int KT = K >> 6;
  for (int kt = 0; kt < KT; ++kt) {
    const int k0 = kt << 6;
#pragma unroll
    for (int i = 0; i < 4; ++i) {
      load_lds16(A + aSrc[i] + k0, (char*)lA + (i * 256 + tid) * 16);
      load_lds16(Bt + bSrc[i] + k0, (char*)lB + (i * 256 + tid) * 16);
    }
    __syncthreads();
#pragma unroll
    for (int kk = 0; kk < 2; ++kk) {
      const int kb = kk * 64 + lhi * 16;
      bf16x8 bfr[4], af[4];
#pragma unroll
      for (int nf = 0; nf < 4; ++nf) {
        const int rb = wc * 64 + nf * 16 + l15;
        bfr[nf] = *(const bf16x8*)((const char*)lB + rb * 128 + (kb ^ ((rb & 7) << 4)));
      }
#pragma unroll
      for (int mf = 0; mf < 4; ++mf) {
        const int ra = wr * 64 + mf * 16 + l15;
        af[mf] = *(const bf16x8*)((const char*)lA + ra * 128 + (kb ^ ((ra & 7) << 4)));
      }
#pragma unroll
      for (int mf = 0; mf < 4; ++mf)
#pragma unroll
        for (int nf = 0; nf < 4; ++nf)
          acc[mf][nf] = __builtin_amdgcn_mfma_f32_16x16x32_bf16(af[mf], bfr[nf], acc[mf][nf], 0, 0, 0);
    }
    __syncthreads();
  }

  const int row0 = tm * 128 + wr * 64;
  const int col0 = tn * 128 + wc * 64;
  float bj[4];
#pragma unroll
  for (int nf = 0; nf < 4; ++nf) bj[nf] = bias[col0 + nf * 16 + l15];

  float inv_n[4][4];
  if constexpr (EPI == 4) {
    float part[4][4];
#pragma unroll
    for (int mf = 0; mf < 4; ++mf)
#pragma unroll
      for (int r = 0; r < 4; ++r) {
        float p = 0.f;
#pragma unroll
        for (int nf = 0; nf < 4; ++nf) {
          const float v = acc[mf][nf][r] + bj[nf];
          p += v * v;
        }
        part[mf][r] = p;
      }
#pragma unroll
    for (int ms = 1; ms < 16; ms <<= 1)
#pragma unroll
      for (int mf = 0; mf < 4; ++mf)
#pragma unroll
        for (int r = 0; r < 4; ++r) part[mf][r] += __shfl_xor(part[mf][r], ms);
    float* sq = (float*)lA;
    if (l15 == 0) {
#pragma unroll
      for (int mf = 0; mf < 4; ++mf)
#pragma unroll
        for (int r = 0; r < 4; ++r)
          sq[wc * 128 + wr * 64 + mf * 16 + lhi * 4 + r] = part[mf][r];
    }
    __syncthreads();
#pragma unroll
    for (int mf = 0; mf < 4; ++mf)
#pragma unroll
      for (int r = 0; r < 4; ++r) {
        const int idx = wr * 64 + mf * 16 + lhi * 4 + r;
        const float tot = sq[idx] + sq[128 + idx];
        inv_n[mf][r] = nscale / fmaxf(sqrtf(tot), 1e-12f);
      }
  }

#pragma unroll
  for (int mf = 0; mf < 4; ++mf) {
#pragma unroll
    for (int nf = 0; nf < 4; ++nf) {
      const int col = col0 + nf * 16 + l15;
#pragma unroll
      for (int r = 0; r < 4; ++r) {
        const int row = row0 + mf * 16 + lhi * 4 + r;
        const size_t idx = (size_t)row * N + col;
        float v = acc[mf][nf][r] + bj[nf];
        if constexpr (EPI == 0) {
          v = 0.5f * v * (1.f + erff(v * 0.70710678118654752f));
          ((ushort_t*)Out)[idx] = f2bf(v);
        } else if constexpr (EPI == 2) {
          ((float*)Out)[idx] = v;
        } else if constexpr (EPI == 3) {
          ((float*)Out)[idx] = Xres[idx] + v;
        } else {
          ((ushort_t*)Out)[idx] = f2bf(v * inv_n[mf][r]);
        }
      }
    }
  }
}

// ---------------------------------------------------------------- GEMM split-K
// gemm_s core with K split in 2: grid = ntiles*2; swz pairs (both k-halves of
// one tile) stay on one XCD. Writes fp32 partials (no bias) to Part.
__global__ __launch_bounds__(256, 3)
void gemm_sk(const ushort_t* __restrict__ A, const ushort_t* __restrict__ Bt,
             float* __restrict__ Part, int N, int Kslice, int LDK, int GM,
             size_t pstride) {
  __shared__ ushort_t lA[128 * 64];
  __shared__ ushort_t lB[128 * 64];

  const int tid = threadIdx.x;
  const int lane = tid & 63;
  const int w = tid >> 6;
  const int l15 = lane & 15, lhi = lane >> 4;
  const int wr = w >> 1, wc = w & 1;

  const int nwg = gridDim.x;
  const int cpx = nwg >> 3;
  const int swz = (blockIdx.x & 7) * cpx + (blockIdx.x >> 3);
  const int ks = swz & 1;
  const int tile = swz >> 1;
  const int tm = tile % GM, tn = tile / GM;

  const ushort_t* Ab = A + (size_t)ks * Kslice;
  const ushort_t* Bb = Bt + (size_t)ks * Kslice;

  size_t aSrc[4], bSrc[4];
#pragma unroll
  for (int i = 0; i < 4; ++i) {
    const int ch = i * 256 + tid;
    const int row = ch >> 3;
    const int colb = ((ch & 7) * 16) ^ ((row & 7) << 4);
    aSrc[i] = (size_t)(tm * 128 + row) * LDK + (colb >> 1);
    bSrc[i] = (size_t)(tn * 128 + row) * LDK + (colb >> 1);
  }

  f32x4 acc[4][4] = {};

  const int KT = Kslice >> 6;
  for (int kt = 0; kt < KT; ++kt) {
    const int k0 = kt << 6;
#pragma unroll
    for (int i = 0; i < 4; ++i) {
      load_lds16(Ab + aSrc[i] + k0, (char*)lA + (i * 256 + tid) * 16);
      load_lds16(Bb + bSrc[i] + k0, (char*)lB + (i * 256 + tid) * 16);
    }
    __syncthreads();
#pragma unroll
    for (int kk = 0; kk < 2; ++kk) {
      const int kb = kk * 64 + lhi * 16;
      bf16x8 bfr[4], af[4];
#pragma unroll
      for (int nf = 0; nf < 4; ++nf) {
        const int rb = wc * 64 + nf * 16 + l15;
        bfr[nf] = *(const bf16x8*)((const char*)lB + rb * 128 + (kb ^ ((rb & 7) << 4)));
      }
#pragma unroll
      for (int mf = 0; mf < 4; ++mf) {
        const int ra = wr * 64 + mf * 16 + l15;
        af[mf] = *(const bf16x8*)((const char*)lA + ra * 128 + (kb ^ ((ra & 7) << 4)));
      }
#pragma unroll
      for (int mf = 0; mf < 4; ++mf)
#pragma unroll
        for (int nf = 0; nf < 4; ++nf)
          acc[mf][nf] = __builtin_amdgcn_mfma_f32_16x16x32_bf16(af[mf], bfr[nf], acc[mf][nf], 0, 0, 0);
    }
    __syncthreads();
  }

  const int row0 = tm * 128 + wr * 64;
  const int col0 = tn * 128 + wc * 64;
  float* outp = Part + (size_t)ks * pstride;
#pragma unroll
  for (int mf = 0; mf < 4; ++mf)
#pragma unroll
    for (int nf = 0; nf < 4; ++nf) {
      const int col = col0 + nf * 16 + l15;
#pragma unroll
      for (int r = 0; r < 4; ++r) {
        const int row = row0 + mf * 16 + lhi * 4 + r;
        outp[(size_t)row * N + col] = acc[mf][nf][r];
      }
    }
}

// ---------------------------------------------------------------- split-K reduce
// out = p0 + p1 + bias (+ Xres). N=2048 fixed (bias float4 idx = i & 511).
template <int WITH_RES>
__global__ __launch_bounds__(256)
void redk(const float* __restrict__ P, const float* __restrict__ bias,
          const float* __restrict__ Xres, float* __restrict__ out,
          int n4, int pstride4) {
  int i = blockIdx.x * 256 + threadIdx.x;
  const int stride = gridDim.x * 256;
  for (; i < n4; i += stride) {
    float4 a = ((const float4*)P)[i];
    float4 b = ((const float4*)P)[i + pstride4];
    float4 bv = ((const float4*)bias)[i & 511];
    float4 r;
    r.x = a.x + b.x + bv.x;
    r.y = a.y + b.y + bv.y;
    r.z = a.z + b.z + bv.z;
    r.w = a.w + b.w + bv.w;
    if constexpr (WITH_RES) {
      float4 xr = ((const float4*)Xres)[i];
      r.x += xr.x; r.y += xr.y; r.z += xr.z; r.w += xr.w;
    }
    ((float4*)out)[i] = r;
  }
}

// ---------------------------------------------------------------- GEMM 128x256
// (R11 proven): BK=64, single-buf 48KB, 8 waves, (512,4) -> 2 blocks/CU.
// EPI: 0 bias+gelu->bf16 ; 4 per-128-col-segment l2norm*nscale -> bf16
template <int EPI>
__global__ __launch_bounds__(512, 4)
void gemm_w(const ushort_t* __restrict__ A, const ushort_t* __restrict__ Bt,
            const float* __restrict__ bias, void* __restrict__ Out,
            int N, int K, int GM, float nscale) {
  __shared__ ushort_t lA[128 * 64];
  __shared__ ushort_t lB[256 * 64];

  const int tid = threadIdx.x;
  const int lane = tid & 63;
  const int w = tid >> 6;
  const int l15 = lane & 15, lhi = lane >> 4;
  const int wr = w >> 2, wc = w & 3;

  const int nwg = gridDim.x;
  const int cpx = nwg >> 3;
  const int swz = (blockIdx.x & 7) * cpx + (blockIdx.x >> 3);
  const int tm = swz % GM, tn = swz / GM;

  size_t aSrc[2], bSrc[4];
#pragma unroll
  for (int i = 0; i < 2; ++i) {
    const int ch = i * 512 + tid;
    const int row = ch >> 3;
    const int colb = ((ch & 7) * 16) ^ ((row & 7) << 4);
    aSrc[i] = (size_t)(tm * 128 + row) * K + (colb >> 1);
  }
#pragma unroll
  for (int i = 0; i < 4; ++i) {
    const int ch = i * 512 + tid;
    const int row = ch >> 3;
    const int colb = ((ch & 7) * 16) ^ ((row & 7) << 4);
    bSrc[i] = (size_t)(tn * 256 + row) * K + (colb >> 1);
  }

  f32x4 acc[4][4] = {};

  const int KT = K >> 6;
  for (int kt = 0; kt < KT; ++kt) {
    const int k0 = kt << 6;
#pragma unroll
    for (int i = 0; i < 2; ++i)
      load_lds16(A + aSrc[i] + k0, (char*)lA + (i * 512 + tid) * 16);
#pragma unroll
    for (int i = 0; i < 4; ++i)
      load_lds16(Bt + bSrc[i] + k0, (char*)lB + (i * 512 + tid) * 16);
    __syncthreads();
#pragma unroll
    for (int kk = 0; kk < 2; ++kk) {
      const int kb = kk * 64 + lhi * 16;
      bf16x8 bfr[4], af[4];
#pragma unroll
      for (int nf = 0; nf < 4; ++nf) {
        const int rb = wc * 64 + nf * 16 + l15;
        bfr[nf] = *(const bf16x8*)((const char*)lB + rb * 128 + (kb ^ ((rb & 7) << 4)));
      }
#pragma unroll
      for (int mf = 0; mf < 4; ++mf) {
        const int ra = wr * 64 + mf * 16 + l15;
        af[mf] = *(const bf16x8*)((const char*)lA + ra * 128 + (kb ^ ((ra & 7) << 4)));
      }
#pragma unroll
      for (int mf = 0; mf < 4; ++mf)
#pragma unroll
        for (int nf = 0; nf < 4; ++nf)
          acc[mf][nf] = __builtin_amdgcn_mfma_f32_16x16x32_bf16(af[mf], bfr[nf], acc[mf][nf], 0, 0, 0);
    }
    __syncthreads();
  }

  const int row0 = tm * 128 + wr * 64;
  const int col0 = tn * 256 + wc * 64;
  float bj[4];
#pragma unroll
  for (int nf = 0; nf < 4; ++nf) bj[nf] = bias[col0 + nf * 16 + l15];

  float inv_n[4][4];
  if constexpr (EPI == 4) {
    float part[4][4];
#pragma unroll
    for (int mf = 0; mf < 4; ++mf)
#pragma unroll
      for (int r = 0; r < 4; ++r) {
        float p = 0.f;
#pragma unroll
        for (int nf = 0; nf < 4; ++nf) {
          const float v = acc[mf][nf][r] + bj[nf];
          p += v * v;
        }
        part[mf][r] = p;
      }
#pragma unroll
    for (int ms = 1; ms < 16; ms <<= 1)
#pragma unroll
      for (int mf = 0; mf < 4; ++mf)
#pragma unroll
        for (int r = 0; r < 4; ++r) part[mf][r] += __shfl_xor(part[mf][r], ms);
    float* sq = (float*)lA;  // [4 wc][128 rows]
    if (l15 == 0) {
#pragma unroll
      for (int mf = 0; mf < 4; ++mf)
#pragma unroll
        for (int r = 0; r < 4; ++r)
          sq[wc * 128 + wr * 64 + mf * 16 + lhi * 4 + r] = part[mf][r];
    }
    __syncthreads();
#pragma unroll
    for (int mf = 0; mf < 4; ++mf)
#pragma unroll
      for (int r = 0; r < 4; ++r) {
        const int idx = wr * 64 + mf * 16 + lhi * 4 + r;
        const float tot = sq[wc * 128 + idx] + sq[(wc ^ 1) * 128 + idx];
        inv_n[mf][r] = nscale / fmaxf(sqrtf(tot), 1e-12f);
      }
  }

#pragma unroll
  for (int mf = 0; mf < 4; ++mf) {
#pragma unroll
    for (int nf = 0; nf < 4; ++nf) {
      const int col = col0 + nf * 16 + l15;
#pragma unroll
      for (int r = 0; r < 4; ++r) {
        const int row = row0 + mf * 16 + lhi * 4 + r;
        const size_t idx = (size_t)row * N + col;
        float v = acc[mf][nf][r] + bj[nf];
        if constexpr (EPI == 0) {
          v = 0.5f * v * (1.f + erff(v * 0.70710678118654752f));
          ((ushort_t*)Out)[idx] = f2bf(v);
        } else {
          ((ushort_t*)Out)[idx] = f2bf(v * inv_n[mf][r]);
        }
      }
    }
  }
}

// ---------------------------------------------------------------- attention
// (unchanged from R8)
__global__ __launch_bounds__(512, 4)
void attn_k(const ushort_t* __restrict__ Q, const ushort_t* __restrict__ KV,
            const ushort_t* __restrict__ VT,
            const unsigned long long* __restrict__ PM,
            ushort_t* __restrict__ CTX) {
  __shared__ ushort_t lk[2][64 * 128];
  __shared__ ushort_t lvt[2][128 * 64];
  __shared__ ushort_t lp[8][16 * 64];

  const int tid = threadIdx.x, lane = tid & 63, w = tid >> 6;
  const int l15 = lane & 15, lhi = lane >> 4;
  const int wid = ((blockIdx.x & 7) << 6) + (blockIdx.x >> 3);
  const int qt = wid & 15, pair = wid >> 4;
  const int b = pair >> 4, h = pair & 15;

  size_t kSrc[2], vSrc[2];
  int kDst[2], vDst[2];
#pragma unroll
  for (int i = 0; i < 2; ++i) {
    const int ch = (i * 8 + w) * 64 + lane;
    {
      const int row = ch >> 4;
      const int cb = ((ch & 15) * 16) ^ ((row & 7) << 4);
      kSrc[i] = ((size_t)row * 2 + b) * 4096 + h * 256 + (cb >> 1);
      kDst[i] = (i * 8 + w) * 1024;
    }
    {
      const int row = ch >> 3;
      const int cb = ((ch & 7) * 16) ^ ((row & 7) << 4);
      vSrc[i] = (size_t)pair * 128 * 4096 + (size_t)row * 4096 + (cb >> 1);
      vDst[i] = (i * 8 + w) * 1024;
    }
  }

  bf16x8 aq[4];
  {
    const ushort_t* qbase =
        Q + ((size_t)(qt * 128 + w * 16 + l15) * 2 + b) * 2048 + h * 128 + lhi * 8;
#pragma unroll
    for (int kk = 0; kk < 4; ++kk) aq[kk] = *(const bf16x8*)(qbase + kk * 32);
  }

  float l_acc[4] = {0.f, 0.f, 0.f, 0.f};
  f32x4 acc_o[8] = {};
  const unsigned long long* mrow =
      PM + (size_t)(b * 2048 + qt * 128 + w * 16 + lhi * 4) * 64;
  const int l15p16 = l15 + 16;

#pragma unroll
  for (int i = 0; i < 2; ++i) {
    load_lds16(KV + kSrc[i], (char*)lk[0] + kDst[i]);
    load_lds16(VT + vSrc[i], (char*)lvt[0] + vDst[i]);
  }
  __syncthreads();

  int cur = 0;
  for (int t = 0; t < 64; ++t) {
    if (t < 63) {
      const size_t kAdd = (size_t)(t + 1) * 64 * 8192;
      const int vAdd = (t + 1) * 64;
#pragma unroll
      for (int i = 0; i < 2; ++i) {
        load_lds16(KV + kSrc[i] + kAdd, (char*)lk[cur ^ 1] + kDst[i]);
        load_lds16(VT + vSrc[i] + vAdd, (char*)lvt[cur ^ 1] + vDst[i]);
      }
    }
    unsigned long long mw[4];
#pragma unroll
    for (int r = 0; r < 4; ++r) mw[r] = mrow[r * 64 + t];

    f32x4 sa[4] = {};
#pragma unroll
    for (int kk = 0; kk < 4; ++kk) {
#pragma unroll
      for (int j = 0; j < 4; ++j) {
        const int krow = j * 16 + l15;
        const int bcb = (kk * 64 + lhi * 16) ^ ((krow & 7) << 4);
        bf16x8 bk = *(const bf16x8*)((const char*)lk[cur] + krow * 256 + bcb);
        sa[j] = __builtin_amdgcn_mfma_f32_16x16x32_bf16(aq[kk], bk, sa[j], 0, 0, 0);
      }
    }

#pragma unroll
    for (int r = 0; r < 4; ++r) {
      const unsigned int mlo = (unsigned int)mw[r];
      const unsigned int mhi = (unsigned int)(mw[r] >> 32);
#pragma unroll
      for (int j = 0; j < 4; ++j) {
        const unsigned int sel = (j < 2) ? mlo : mhi;
        const int sh = (j & 1) ? l15p16 : l15;
        const bool mk = (sel >> sh) & 1u;
        const float p = __expf(sa[j][r]);
        const float pv = mk ? 0.f : p;
        sa[j][r] = pv;
        l_acc[r] += pv;
      }
    }

#pragma unroll
    for (int r = 0; r < 4; ++r) {
      unsigned int pk0, pk1;
      asm("v_cvt_pk_bf16_f32 %0, %1, %2" : "=v"(pk0) : "v"(sa[0][r]), "v"(sa[1][r]));
      asm("v_cvt_pk_bf16_f32 %0, %1, %2" : "=v"(pk1) : "v"(sa[2][r]), "v"(sa[3][r]));
      const int prow = lhi * 4 + r;
      char* base = (char*)lp[w] + prow * 128;
      const int swz = (prow & 7) << 4;
      *(ushort_t*)(base + ((l15 * 2) ^ swz)) = (ushort_t)pk0;
      *(ushort_t*)(base + (((16 + l15) * 2) ^ swz)) = (ushort_t)(pk0 >> 16);
      *(ushort_t*)(base + (((32 + l15) * 2) ^ swz)) = (ushort_t)pk1;
      *(ushort_t*)(base + (((48 + l15) * 2) ^ swz)) = (ushort_t)(pk1 >> 16);
    }

#pragma unroll
    for (int ks = 0; ks < 2; ++ks) {
      const int acb2 = (ks * 64 + lhi * 16) ^ ((l15 & 7) << 4);
      bf16x8 ap = *(const bf16x8*)((const char*)lp[w] + l15 * 128 + acb2);
#pragma unroll
      for (int d = 0; d < 8; ++d) {
        const int vrow = d * 16 + l15;
        const int vcb = (ks * 64 + lhi * 16) ^ ((vrow & 7) << 4);
        bf16x8 bv = *(const bf16x8*)((const char*)lvt[cur] + vrow * 128 + vcb);
        acc_o[d] = __builtin_amdgcn_mfma_f32_16x16x32_bf16(ap, bv, acc_o[d], 0, 0, 0);
      }
    }
    __syncthreads();
    cur ^= 1;
  }

#pragma unroll
  for (int ms = 1; ms < 16; ms <<= 1)
#pragma unroll
    for (int r = 0; r < 4; ++r) l_acc[r] += __shfl_xor(l_acc[r], ms);

#pragma unroll
  for (int r = 0; r < 4; ++r) {
    const float inv = 1.f / fmaxf(l_acc[r], 1e-20f);
    const size_t orow = ((size_t)(qt * 128 + w * 16 + lhi * 4 + r) * 2 + b) * 2048 + h * 128;
#pragma unroll
    for (int d = 0; d < 8; ++d)
      CTX[orow + d * 16 + l15] = f2bf(acc_o[d][r] * inv);
  }
}

// ---------------------------------------------------------------- launch
extern "C" void kernel_launch(void* const* d_in, const int* in_sizes, int n_in,
                              void* d_out, int out_size, void* d_ws, size_t ws_size,
                              hipStream_t stream) {
  (void)in_sizes; (void)n_in; (void)out_size; (void)ws_size;
  const float* x    = (const float*)d_in[0];
  const float* ph   = (const float*)d_in[1];
  const void*  mask = d_in[2];
  const float* ln1g = (const float*)d_in[3];
  const float* ln1b = (const float*)d_in[4];
  const float* ln2g = (const float*)d_in[5];
  const float* ln2b = (const float*)d_in[6];
  const float* ln3g = (const float*)d_in[7];
  const float* ln3b = (const float*)d_in[8];
  const float* w1a  = (const float*)d_in[9];
  const float* b1a  = (const float*)d_in[10];
  const float* w2a  = (const float*)d_in[11];
  const float* b2a  = (const float*)d_in[12];
  const float* w1b  = (const float*)d_in[13];
  const float* b1b  = (const float*)d_in[14];
  const float* w2b  = (const float*)d_in[15];
  const float* b2b  = (const float*)d_in[16];
  const float* wq   = (const float*)d_in[17];
  const float* bq   = (const float*)d_in[18];
  const float* wkv  = (const float*)d_in[19];
  const float* bkv  = (const float*)d_in[20];
  const float* wd   = (const float*)d_in[21];
  const float* bd   = (const float*)d_in[22];

  char* ws = (char*)d_ws;
  int* flag = (int*)ws;
  size_t off = 256;
  auto alloc = [&](size_t bytes) {
    void* p = ws + off;
    off += (bytes + 255) & ~(size_t)255;
    return p;
  };
  ushort_t* WT1   = (ushort_t*)alloc(2048ull * 8192 * 2);
  ushort_t* WT2   = (ushort_t*)alloc(2048ull * 8192 * 2);
  ushort_t* WQT   = (ushort_t*)alloc(2048ull * 2048 * 2);
  ushort_t* WKVT  = (ushort_t*)alloc(2048ull * 4096 * 2);
  ushort_t* WDT   = (ushort_t*)alloc(2048ull * 2048 * 2);
  ushort_t* H1    = (ushort_t*)alloc(4096ull * 2048 * 2);
  ushort_t* GELU  = (ushort_t*)alloc(4096ull * 8192 * 2);
  float*    X     = (float*)alloc(4096ull * 2048 * 4);
  ushort_t* QRAW  = (ushort_t*)alloc(4096ull * 2048 * 2);
  ushort_t* PH16  = (ushort_t*)alloc(8192ull * 2048 * 2);
  ushort_t* KVRAW = (ushort_t*)alloc(8192ull * 4096 * 2);
  ushort_t* VT    = PH16;   // alias: past_hidden bf16 dead after kv GEMM
  ushort_t* CTX   = WKVT;   // alias: wkv^T dead after kv GEMM
  unsigned long long* PMASK = (unsigned long long*)GELU;  // alias, see R1 note
  // split-K partials (2 x 4096x2048 f32 = 64MB) alias KVRAW: free before the
  // KV GEMM writes it (mlp1 down-proj) and after attn's last read (mlp2).
  float* PART = (float*)KVRAW;

  const dim3 tb(32, 8);
  const float SSCALE = 0.088388347648318447f;  // 1/sqrt(128), folded into Q
  const size_t PSTRIDE = 4096ull * 2048;

  detect_mask_k<<<1, 64, 0, stream>>>((const unsigned int*)mask, flag);

  transpose_w<<<dim3(128, 32), 256, 0, stream>>>(w1a, WT1, 2048, 8192);
  transpose_w<<<dim3(32, 128), 256, 0, stream>>>(w2a, WT2, 8192, 2048);
  transpose_w<<<dim3(32, 32), 256, 0, stream>>>(wq, WQT, 2048, 2048);
  transpose_w<<<dim3(64, 32), 256, 0, stream>>>(wkv, WKVT, 2048, 4096);
  transpose_w<<<dim3(32, 32), 256, 0, stream>>>(wd, WDT, 2048, 2048);

  // mlp1 (output REPLACES x); down-proj split-K=2
  ln_kernel<<<4096, 256, 0, stream>>>(x, ln1g, ln1b, H1);
  gemm_w<0><<<1024, 512, 0, stream>>>(H1, WT1, b1a, GELU, 8192, 2048, 32, 0.f);
  gemm_sk<<<1024, 256, 0, stream>>>(GELU, WT2, PART, 2048, 4096, 8192, 32, PSTRIDE);
  redk<0><<<2048, 256, 0, stream>>>(PART, b2a, nullptr, X, 2097152, (int)(PSTRIDE / 4));

  // pack mask now that GELU region is dead
  mask_pack_k<<<1024, 256, 0, stream>>>(mask, flag, PMASK, 262144);

  // attention (l2norm fused into Q/KV GEMM epilogues)
  ln_kernel<<<4096, 256, 0, stream>>>(X, ln2g, ln2b, H1);
  gemm_s<4><<<512, 256, 0, stream>>>(H1, WQT, bq, nullptr, QRAW, 2048, 2048, 32, SSCALE);
  f32_to_bf16_k<<<2048, 256, 0, stream>>>(ph, PH16, 8192 * 2048 / 4);
  gemm_w<4><<<1024, 512, 0, stream>>>(PH16, WKVT, bkv, KVRAW, 4096, 2048, 64, 1.0f);
  vtrans_k<<<dim3(128, 4, 32), tb, 0, stream>>>(KVRAW, VT);
  attn_k<<<512, 512, 0, stream>>>(QRAW, KVRAW, VT, PMASK, CTX);
  gemm_s<3><<<512, 256, 0, stream>>>(CTX, WDT, bd, X, X, 2048, 2048, 32, 0.f);

  // mlp2 (with residual); down-proj split-K=2 (KVRAW dead after attn)
  ln_kernel<<<4096, 256, 0, stream>>>(X, ln3g, ln3b, H1);
  transpose_w<<<dim3(128, 32), 256, 0, stream>>>(w1b, WT1, 2048, 8192);
  transpose_w<<<dim3(32, 128), 256, 0, stream>>>(w2b, WT2, 8192, 2048);
  gemm_w<0><<<1024, 512, 0, stream>>>(H1, WT1, b1b, GELU, 8192, 2048, 32, 0.f);
  gemm_sk<<<1024, 256, 0, stream>>>(GELU, WT2, PART, 2048, 4096, 8192, 32, PSTRIDE);
  redk<1><<<2048, 256, 0, stream>>>(PART, b2b, X, (float*)d_out, 2097152, (int)(PSTRIDE / 4));
}

// Round 14
// 1262.330 us; speedup vs baseline: 1.0524x; 1.0524x over previous
//
#include <hip/hip_runtime.h>

// ParallelMemoryModule: mlp1 -> memory-attention -> mlp2 on MI355X.
// R13: revert R12 split-K (regression). Exact R11 config + 2D XCD patch
// grouping in gemm_w (16x8 tile patch per XCD chunk -> L2 working set
// 34->16MB for KV GEMM; FETCH model confirmed by R12 counters).

typedef unsigned short ushort_t;
typedef __attribute__((ext_vector_type(8))) short bf16x8;
typedef __attribute__((ext_vector_type(4))) float f32x4;

#define DEVI __device__ __forceinline__

DEVI ushort_t f2bf(float f) {
  unsigned int u = __builtin_bit_cast(unsigned int, f);
  u += 0x7FFFu + ((u >> 16) & 1u);
  return (ushort_t)(u >> 16);
}
DEVI float bf2f(ushort_t h) {
  unsigned int u = ((unsigned int)h) << 16;
  return __builtin_bit_cast(float, u);
}

DEVI void load_lds16(const void* g, void* l) {
  __builtin_amdgcn_global_load_lds(
      (__attribute__((address_space(1))) void*)(g),
      (__attribute__((address_space(3))) void*)(l), 16, 0, 0);
}

// ---------------------------------------------------------------- mask dtype
__global__ void detect_mask_k(const unsigned int* __restrict__ m, int* __restrict__ flag) {
  unsigned int v = m[threadIdx.x];
  unsigned long long ok = __ballot(v <= 1u);
  if (threadIdx.x == 0) *flag = (ok == ~0ull) ? 1 : 0;
}

// ---------------------------------------------------------------- mask pack
__global__ __launch_bounds__(256)
void mask_pack_k(const void* __restrict__ maskp, const int* __restrict__ mtype,
                 unsigned long long* __restrict__ out, int nwords) {
  const int mint = *mtype;
  const int lane = threadIdx.x & 63;
  const int wglob = blockIdx.x * 4 + (threadIdx.x >> 6);
  const int nw = gridDim.x * 4;
  const unsigned char* m8 = (const unsigned char*)maskp;
  const int* m32 = (const int*)maskp;
  for (int i = wglob; i < nwords; i += nw) {
    const size_t e = (size_t)i * 64 + lane;
    const bool v = mint ? (m32[e] != 0) : (m8[e] != 0);
    unsigned long long bits = __ballot(v);
    if (lane == 0) out[i] = bits;
  }
}

// ---------------------------------------------------------------- transpose W
__global__ __launch_bounds__(256)
void transpose_w(const float* __restrict__ in, ushort_t* __restrict__ out, int K, int N) {
  __shared__ float t[64][65];
  const int tid = threadIdx.x;
  const int tx = tid & 63, ty = tid >> 6;
  const int n0 = blockIdx.x * 64, k0 = blockIdx.y * 64;
#pragma unroll
  for (int i = 0; i < 16; ++i)
    t[ty + i * 4][tx] = in[(size_t)(k0 + ty + i * 4) * N + n0 + tx];
  __syncthreads();
  const int l32 = tid & 31, nr = tid >> 5;
#pragma unroll
  for (int i = 0; i < 8; ++i) {
    const int n = nr + i * 8;
    ushort2 o;
    o.x = f2bf(t[2 * l32][n]);
    o.y = f2bf(t[2 * l32 + 1][n]);
    *(ushort2*)&out[(size_t)(n0 + n) * K + k0 + 2 * l32] = o;
  }
}

// ---------------------------------------------------------------- f32->bf16
__global__ void f32_to_bf16_k(const float* __restrict__ in, ushort_t* __restrict__ out, int n4) {
  int i = blockIdx.x * blockDim.x + threadIdx.x;
  int stride = gridDim.x * blockDim.x;
  for (; i < n4; i += stride) {
    float4 v = ((const float4*)in)[i];
    ushort4 o;
    o.x = f2bf(v.x); o.y = f2bf(v.y); o.z = f2bf(v.z); o.w = f2bf(v.w);
    ((ushort4*)out)[i] = o;
  }
}

// ---------------------------------------------------------------- layernorm
__global__ __launch_bounds__(256)
void ln_kernel(const float* __restrict__ in, const float* __restrict__ gam,
               const float* __restrict__ bet, ushort_t* __restrict__ out) {
  const int row = blockIdx.x;
  const float* p = in + (size_t)row * 2048;
  const int tid = threadIdx.x;
  float4 v0 = ((const float4*)p)[tid * 2];
  float4 v1 = ((const float4*)p)[tid * 2 + 1];
  float s = v0.x + v0.y + v0.z + v0.w + v1.x + v1.y + v1.z + v1.w;
  float q = v0.x * v0.x + v0.y * v0.y + v0.z * v0.z + v0.w * v0.w +
            v1.x * v1.x + v1.y * v1.y + v1.z * v1.z + v1.w * v1.w;
#pragma unroll
  for (int m = 1; m < 64; m <<= 1) { s += __shfl_xor(s, m); q += __shfl_xor(q, m); }
  __shared__ float red[8];
  const int w = tid >> 6;
  if ((tid & 63) == 0) { red[w] = s; red[4 + w] = q; }
  __syncthreads();
  s = red[0] + red[1] + red[2] + red[3];
  q = red[4] + red[5] + red[6] + red[7];
  const float mean = s * (1.f / 2048.f);
  const float var = q * (1.f / 2048.f) - mean * mean;
  const float rs = rsqrtf(var + 1e-5f);
  float4 g0 = ((const float4*)gam)[tid * 2], g1 = ((const float4*)gam)[tid * 2 + 1];
  float4 b0 = ((const float4*)bet)[tid * 2], b1 = ((const float4*)bet)[tid * 2 + 1];
  ushort4 o0, o1;
  o0.x = f2bf((v0.x - mean) * rs * g0.x + b0.x);
  o0.y = f2bf((v0.y - mean) * rs * g0.y + b0.y);
  o0.z = f2bf((v0.z - mean) * rs * g0.z + b0.z);
  o0.w = f2bf((v0.w - mean) * rs * g0.w + b0.w);
  o1.x = f2bf((v1.x - mean) * rs * g1.x + b1.x);
  o1.y = f2bf((v1.y - mean) * rs * g1.y + b1.y);
  o1.z = f2bf((v1.z - mean) * rs * g1.z + b1.z);
  o1.w = f2bf((v1.w - mean) * rs * g1.w + b1.w);
  ushort4* ob = (ushort4*)(out + (size_t)row * 2048);
  ob[tid * 2] = o0;
  ob[tid * 2 + 1] = o1;
}

// ---------------------------------------------------------------- V transpose
__global__ __launch_bounds__(256)
void vtrans_k(const ushort_t* __restrict__ kv, ushort_t* __restrict__ vt) {
  __shared__ ushort_t t[32][33];
  const int tx = threadIdx.x, ty = threadIdx.y;
  const int m0 = blockIdx.x * 32, d0 = blockIdx.y * 32, bh = blockIdx.z;
  const int b = bh >> 4, h = bh & 15;
#pragma unroll
  for (int i = 0; i < 4; ++i)
    t[ty + i * 8][tx] = kv[((size_t)(m0 + ty + i * 8) * 2 + b) * 4096 + h * 256 + 128 + d0 + tx];
  __syncthreads();
#pragma unroll
  for (int i = 0; i < 4; ++i)
    vt[((size_t)bh * 128 + d0 + ty + i * 8) * 4096 + m0 + tx] = t[tx][ty + i * 8];
}

// ---------------------------------------------------------------- GEMM 128^2
// m97-class (PROVEN): 128x128, BK=64, 4 waves, single-buf 32KB, 2-barrier,
// 3 blocks/CU (124 regs/thread: VGPR 60 + AGPR 64).
// EPI: 0 bias+gelu->bf16 ; 2 bias->f32 ; 3 Xres+acc+bias->f32 ;
//      4 l2norm(row over 128 tile cols)*nscale -> bf16
template <int EPI>
__global__ __launch_bounds__(256, 3)
void gemm_s(const ushort_t* __restrict__ A, const ushort_t* __restrict__ Bt,
            const float* __restrict__ bias, const float* __restrict__ Xres,
            void* __restrict__ Out, int N, int K, int GM, float nscale) {
  __shared__ ushort_t lA[128 * 64];
  __shared__ ushort_t lB[128 * 64];

  const int tid = threadIdx.x;
  const int lane = tid & 63;
  const int w = tid >> 6;
  const int l15 = lane & 15, lhi = lane >> 4;
  const int wr = w >> 1, wc = w & 1;

  const int nwg = gridDim.x;
  const int cpx = nwg >> 3;
  const int swz = (blockIdx.x & 7) * cpx + (blockIdx.x >> 3);
  const int tm = swz % GM, tn = swz / GM;

  size_t aSrc[4], bSrc[4];
#pragma unroll
  for (int i = 0; i < 4; ++i) {
    const int ch = i * 256 + tid;
    const int row = ch >> 3;
    const int colb = ((ch & 7) * 16) ^ ((row & 7) << 4);
    aSrc[i] = (size_t)(tm * 128 + row) * K + (colb >> 1);
    bSrc[i] = (size_t)(tn * 128 + row) * K + (colb >> 1);
  }

  f32x4 acc[4][4] = {};

  const int KT = K >> 6;
  for (int kt = 0; kt < KT; ++kt) {
    const int k0 = kt << 6;
#pragma unroll
    for (int i = 0; i < 4; ++i) {
      load_lds16(A + aSrc[i] + k0, (char*)lA + (i * 256 + tid) * 16);
      load_lds16(Bt + bSrc[i] + k0, (char*)lB + (i * 256 + tid) * 16);
    }
    __syncthreads();
#pragma unroll
    for (int kk = 0; kk < 2; ++kk) {
      const int kb = kk * 64 + lhi * 16;
      bf16x8 bfr[4], af[4];
#pragma unroll
      for (int nf = 0; nf < 4; ++nf) {
        const int rb = wc * 64 + nf * 16 + l15;
        bfr[nf] = *(const bf16x8*)((const char*)lB + rb * 128 + (kb ^ ((rb & 7) << 4)));
      }
#pragma unroll
      for (int mf = 0; mf < 4; ++mf) {
        const int ra = wr * 64 + mf * 16 + l15;
        af[mf] = *(const bf16x8*)((const char*)lA + ra * 128 + (kb ^ ((ra & 7) << 4)));
      }
#pragma unroll
      for (int mf = 0; mf < 4; ++mf)
#pragma unroll
        for (int nf = 0; nf < 4; ++nf)
          acc[mf][nf] = __builtin_amdgcn_mfma_f32_16x16x32_bf16(af[mf], bfr[nf], acc[mf][nf], 0, 0, 0);
    }
    __syncthreads();
  }

  const int row0 = tm * 128 + wr * 64;
  const int col0 = tn * 128 + wc * 64;
  float bj[4];
#pragma unroll
  for (int nf = 0; nf < 4; ++nf) bj[nf] = bias[col0 + nf * 16 + l15];

  float inv_n[4][4];
  if constexpr (EPI == 4) {
    float part[4][4];
#pragma unroll
    for (int mf = 0; mf < 4; ++mf)
#pragma unroll
      for (int r = 0; r < 4; ++r) {
        float p = 0.f;
#pragma unroll
        for (int nf = 0; nf < 4; ++nf) {
          const float v = acc[mf][nf][r] + bj[nf];
          p += v * v;
        }
        part[mf][r] = p;
      }
#pragma unroll
    for (int ms = 1; ms < 16; ms <<= 1)
#pragma unroll
      for (int mf = 0; mf < 4; ++mf)
#pragma unroll
        for (int r = 0; r < 4; ++r) part[mf][r] += __shfl_xor(part[mf][r], ms);
    float* sq = (float*)lA;
    if (l15 == 0) {
#pragma unroll
      for (int mf = 0; mf < 4; ++mf)
#pragma unroll
        for (int r = 0; r < 4; ++r)
          sq[wc * 128 + wr * 64 + mf * 16 + lhi * 4 + r] = part[mf][r];
    }
    __syncthreads();
#pragma unroll
    for (int mf = 0; mf < 4; ++mf)
#pragma unroll
      for (int r = 0; r < 4; ++r) {
        const int idx = wr * 64 + mf * 16 + lhi * 4 + r;
        const float tot = sq[idx] + sq[128 + idx];
        inv_n[mf][r] = nscale / fmaxf(sqrtf(tot), 1e-12f);
      }
  }

#pragma unroll
  for (int mf = 0; mf < 4; ++mf) {
#pragma unroll
    for (int nf = 0; nf < 4; ++nf) {
      const int col = col0 + nf * 16 + l15;
#pragma unroll
      for (int r = 0; r < 4; ++r) {
        const int row = row0 + mf * 16 + lhi * 4 + r;
        const size_t idx = (size_t)row * N + col;
        float v = acc[mf][nf][r] + bj[nf];
        if constexpr (EPI == 0) {
          v = 0.5f * v * (1.f + erff(v * 0.70710678118654752f));
          ((ushort_t*)Out)[idx] = f2bf(v);
        } else if constexpr (EPI == 2) {
          ((float*)Out)[idx] = v;
        } else if constexpr (EPI == 3) {
          ((float*)Out)[idx] = Xres[idx] + v;
        } else {
          ((ushort_t*)Out)[idx] = f2bf(v * inv_n[mf][r]);
        }
      }
    }
  }
}

// ---------------------------------------------------------------- GEMM 128x256
// (R11 proven): BK=64, single-buf 48KB, 8 waves, (512,4) -> 2 blocks/CU.
// XCD mapping: each XCD's 128-block chunk is a 16(tm) x 8(tn) patch
// (tm = (xcd%GX)*16 + c&15, tn = (xcd/GX)*8 + c>>4) -> per-XCD L2 working
// set ~16MB (vs 34MB column mapping; R12 FETCH model).
// EPI: 0 bias+gelu->bf16 ; 4 per-128-col-segment l2norm*nscale -> bf16
template <int EPI>
__global__ __launch_bounds__(512, 4)
void gemm_w(const ushort_t* __restrict__ A, const ushort_t* __restrict__ Bt,
            const float* __restrict__ bias, void* __restrict__ Out,
            int N, int K, int GX, float nscale) {
  __shared__ ushort_t lA[128 * 64];
  __shared__ ushort_t lB[256 * 64];

  const int tid = threadIdx.x;
  const int lane = tid & 63;
  const int w = tid >> 6;
  const int l15 = lane & 15, lhi = lane >> 4;
  const int wr = w >> 2, wc = w & 3;

  // 2D XCD patch mapping (grid 1024; 16x8 tile patch per XCD)
  const int xcd = blockIdx.x & 7;
  const int c = blockIdx.x >> 3;
  const int tm = (xcd % GX) * 16 + (c & 15);
  const int tn = (xcd / GX) * 8 + (c >> 4);

  size_t aSrc[2], bSrc[4];
#pragma unroll
  for (int i = 0; i < 2; ++i) {
    const int ch = i * 512 + tid;
    const int row = ch >> 3;
    const int colb = ((ch & 7) * 16) ^ ((row & 7) << 4);
    aSrc[i] = (size_t)(tm * 128 + row) * K + (colb >> 1);
  }
#pragma unroll
  for (int i = 0; i < 4; ++i) {
    const int ch = i * 512 + tid;
    const int row = ch >> 3;
    const int colb = ((ch & 7) * 16) ^ ((row & 7) << 4);
    bSrc[i] = (size_t)(tn * 256 + row) * K + (colb >> 1);
  }

  f32x4 acc[4][4] = {};

  const int KT = K >> 6;
  for (int kt = 0; kt < KT; ++kt) {
    const int k0 = kt << 6;
#pragma unroll
    for (int i = 0; i < 2; ++i)
      load_lds16(A + aSrc[i] + k0, (char*)lA + (i * 512 + tid) * 16);
#pragma unroll
    for (int i = 0; i < 4; ++i)
      load_lds16(Bt + bSrc[i] + k0, (char*)lB + (i * 512 + tid) * 16);
    __syncthreads();
#pragma unroll
    for (int kk = 0; kk < 2; ++kk) {
      const int kb = kk * 64 + lhi * 16;
      bf16x8 bfr[4], af[4];
#pragma unroll
      for (int nf = 0; nf < 4; ++nf) {
        const int rb = wc * 64 + nf * 16 + l15;
        bfr[nf] = *(const bf16x8*)((const char*)lB + rb * 128 + (kb ^ ((rb & 7) << 4)));
      }
#pragma unroll
      for (int mf = 0; mf < 4; ++mf) {
        const int ra = wr * 64 + mf * 16 + l15;
        af[mf] = *(const bf16x8*)((const char*)lA + ra * 128 + (kb ^ ((ra & 7) << 4)));
      }
#pragma unroll
      for (int mf = 0; mf < 4; ++mf)
#pragma unroll
        for (int nf = 0; nf < 4; ++nf)
          acc[mf][nf] = __builtin_amdgcn_mfma_f32_16x16x32_bf16(af[mf], bfr[nf], acc[mf][nf], 0, 0, 0);
    }
    __syncthreads();
  }

  const int row0 = tm * 128 + wr * 64;
  const int col0 = tn * 256 + wc * 64;
  float bj[4];
#pragma unroll
  for (int nf = 0; nf < 4; ++nf) bj[nf] = bias[col0 + nf * 16 + l15];

  float inv_n[4][4];
  if constexpr (EPI == 4) {
    float part[4][4];
#pragma unroll
    for (int mf = 0; mf < 4; ++mf)
#pragma unroll
      for (int r = 0; r < 4; ++r) {
        float p = 0.f;
#pragma unroll
        for (int nf = 0; nf < 4; ++nf) {
          const float v = acc[mf][nf][r] + bj[nf];
          p += v * v;
        }
        part[mf][r] = p;
      }
#pragma unroll
    for (int ms = 1; ms < 16; ms <<= 1)
#pragma unroll
      for (int mf = 0; mf < 4; ++mf)
#pragma unroll
        for (int r = 0; r < 4; ++r) part[mf][r] += __shfl_xor(part[mf][r], ms);
    float* sq = (float*)lA;  // [4 wc][128 rows]
    if (l15 == 0) {
#pragma unroll
      for (int mf = 0; mf < 4; ++mf)
#pragma unroll
        for (int r = 0; r < 4; ++r)
          sq[wc * 128 + wr * 64 + mf * 16 + lhi * 4 + r] = part[mf][r];
    }
    __syncthreads();
#pragma unroll
    for (int mf = 0; mf < 4; ++mf)
#pragma unroll
      for (int r = 0; r < 4; ++r) {
        const int idx = wr * 64 + mf * 16 + lhi * 4 + r;
        const float tot = sq[wc * 128 + idx] + sq[(wc ^ 1) * 128 + idx];
        inv_n[mf][r] = nscale / fmaxf(sqrtf(tot), 1e-12f);
      }
  }

#pragma unroll
  for (int mf = 0; mf < 4; ++mf) {
#pragma unroll
    for (int nf = 0; nf < 4; ++nf) {
      const int col = col0 + nf * 16 + l15;
#pragma unroll
      for (int r = 0; r < 4; ++r) {
        const int row = row0 + mf * 16 + lhi * 4 + r;
        const size_t idx = (size_t)row * N + col;
        float v = acc[mf][nf][r] + bj[nf];
        if constexpr (EPI == 0) {
          v = 0.5f * v * (1.f + erff(v * 0.70710678118654752f));
          ((ushort_t*)Out)[idx] = f2bf(v);
        } else {
          ((ushort_t*)Out)[idx] = f2bf(v * inv_n[mf][r]);
        }
      }
    }
  }
}

// ---------------------------------------------------------------- attention
// (unchanged from R8)
__global__ __launch_bounds__(512, 4)
void attn_k(const ushort_t* __restrict__ Q, const ushort_t* __restrict__ KV,
            const ushort_t* __restrict__ VT,
            const unsigned long long* __restrict__ PM,
            ushort_t* __restrict__ CTX) {
  __shared__ ushort_t lk[2][64 * 128];
  __shared__ ushort_t lvt[2][128 * 64];
  __shared__ ushort_t lp[8][16 * 64];

  const int tid = threadIdx.x, lane = tid & 63, w = tid >> 6;
  const int l15 = lane & 15, lhi = lane >> 4;
  const int wid = ((blockIdx.x & 7) << 6) + (blockIdx.x >> 3);
  const int qt = wid & 15, pair = wid >> 4;
  const int b = pair >> 4, h = pair & 15;

  size_t kSrc[2], vSrc[2];
  int kDst[2], vDst[2];
#pragma unroll
  for (int i = 0; i < 2; ++i) {
    const int ch = (i * 8 + w) * 64 + lane;
    {
      const int row = ch >> 4;
      const int cb = ((ch & 15) * 16) ^ ((row & 7) << 4);
      kSrc[i] = ((size_t)row * 2 + b) * 4096 + h * 256 + (cb >> 1);
      kDst[i] = (i * 8 + w) * 1024;
    }
    {
      const int row = ch >> 3;
      const int cb = ((ch & 7) * 16) ^ ((row & 7) << 4);
      vSrc[i] = (size_t)pair * 128 * 4096 + (size_t)row * 4096 + (cb >> 1);
      vDst[i] = (i * 8 + w) * 1024;
    }
  }

  bf16x8 aq[4];
  {
    const ushort_t* qbase =
        Q + ((size_t)(qt * 128 + w * 16 + l15) * 2 + b) * 2048 + h * 128 + lhi * 8;
#pragma unroll
    for (int kk = 0; kk < 4; ++kk) aq[kk] = *(const bf16x8*)(qbase + kk * 32);
  }

  float l_acc[4] = {0.f, 0.f, 0.f, 0.f};
  f32x4 acc_o[8] = {};
  const unsigned long long* mrow =
      PM + (size_t)(b * 2048 + qt * 128 + w * 16 + lhi * 4) * 64;
  const int l15p16 = l15 + 16;

#pragma unroll
  for (int i = 0; i < 2; ++i) {
    load_lds16(KV + kSrc[i], (char*)lk[0] + kDst[i]);
    load_lds16(VT + vSrc[i], (char*)lvt[0] + vDst[i]);
  }
  __syncthreads();

  int cur = 0;
  for (int t = 0; t < 64; ++t) {
    if (t < 63) {
      const size_t kAdd = (size_t)(t + 1) * 64 * 8192;
      const int vAdd = (t + 1) * 64;
#pragma unroll
      for (int i = 0; i < 2; ++i) {
        load_lds16(KV + kSrc[i] + kAdd, (char*)lk[cur ^ 1] + kDst[i]);
        load_lds16(VT + vSrc[i] + vAdd, (char*)lvt[cur ^ 1] + vDst[i]);
      }
    }
    unsigned long long mw[4];
#pragma unroll
    for (int r = 0; r < 4; ++r) mw[r] = mrow[r * 64 + t];

    f32x4 sa[4] = {};
#pragma unroll
    for (int kk = 0; kk < 4; ++kk) {
#pragma unroll
      for (int j = 0; j < 4; ++j) {
        const int krow = j * 16 + l15;
        const int bcb = (kk * 64 + lhi * 16) ^ ((krow & 7) << 4);
        bf16x8 bk = *(const bf16x8*)((const char*)lk[cur] + krow * 256 + bcb);
        sa[j] = __builtin_amdgcn_mfma_f32_16x16x32_bf16(aq[kk], bk, sa[j], 0, 0, 0);
      }
    }

#pragma unroll
    for (int r = 0; r < 4; ++r) {
      const unsigned int mlo = (unsigned int)mw[r];
      const unsigned int mhi = (unsigned int)(mw[r] >> 32);
#pragma unroll
      for (int j = 0; j < 4; ++j) {
        const unsigned int sel = (j < 2) ? mlo : mhi;
        const int sh = (j & 1) ? l15p16 : l15;
        const bool mk = (sel >> sh) & 1u;
        const float p = __expf(sa[j][r]);
        const float pv = mk ? 0.f : p;
        sa[j][r] = pv;
        l_acc[r] += pv;
      }
    }

#pragma unroll
    for (int r = 0; r < 4; ++r) {
      unsigned int pk0, pk1;
      asm("v_cvt_pk_bf16_f32 %0, %1, %2" : "=v"(pk0) : "v"(sa[0][r]), "v"(sa[1][r]));
      asm("v_cvt_pk_bf16_f32 %0, %1, %2" : "=v"(pk1) : "v"(sa[2][r]), "v"(sa[3][r]));
      const int prow = lhi * 4 + r;
      char* base = (char*)lp[w] + prow * 128;
      const int swz = (prow & 7) << 4;
      *(ushort_t*)(base + ((l15 * 2) ^ swz)) = (ushort_t)pk0;
      *(ushort_t*)(base + (((16 + l15) * 2) ^ swz)) = (ushort_t)(pk0 >> 16);
      *(ushort_t*)(base + (((32 + l15) * 2) ^ swz)) = (ushort_t)pk1;
      *(ushort_t*)(base + (((48 + l15) * 2) ^ swz)) = (ushort_t)(pk1 >> 16);
    }

#pragma unroll
    for (int ks = 0; ks < 2; ++ks) {
      const int acb2 = (ks * 64 + lhi * 16) ^ ((l15 & 7) << 4);
      bf16x8 ap = *(const bf16x8*)((const char*)lp[w] + l15 * 128 + acb2);
#pragma unroll
      for (int d = 0; d < 8; ++d) {
        const int vrow = d * 16 + l15;
        const int vcb = (ks * 64 + lhi * 16) ^ ((vrow & 7) << 4);
        bf16x8 bv = *(const bf16x8*)((const char*)lvt[cur] + vrow * 128 + vcb);
        acc_o[d] = __builtin_amdgcn_mfma_f32_16x16x32_bf16(ap, bv, acc_o[d], 0, 0, 0);
      }
    }
    __syncthreads();
    cur ^= 1;
  }

#pragma unroll
  for (int ms = 1; ms < 16; ms <<= 1)
#pragma unroll
    for (int r = 0; r < 4; ++r) l_acc[r] += __shfl_xor(l_acc[r], ms);

#pragma unroll
  for (int r = 0; r < 4; ++r) {
    const float inv = 1.f / fmaxf(l_acc[r], 1e-20f);
    const size_t orow = ((size_t)(qt * 128 + w * 16 + lhi * 4 + r) * 2 + b) * 2048 + h * 128;
#pragma unroll
    for (int d = 0; d < 8; ++d)
      CTX[orow + d * 16 + l15] = f2bf(acc_o[d][r] * inv);
  }
}

// ---------------------------------------------------------------- launch
extern "C" void kernel_launch(void* const* d_in, const int* in_sizes, int n_in,
                              void* d_out, int out_size, void* d_ws, size_t ws_size,
                              hipStream_t stream) {
  (void)in_sizes; (void)n_in; (void)out_size; (void)ws_size;
  const float* x    = (const float*)d_in[0];
  const float* ph   = (const float*)d_in[1];
  const void*  mask = d_in[2];
  const float* ln1g = (const float*)d_in[3];
  const float* ln1b = (const float*)d_in[4];
  const float* ln2g = (const float*)d_in[5];
  const float* ln2b = (const float*)d_in[6];
  const float* ln3g = (const float*)d_in[7];
  const float* ln3b = (const float*)d_in[8];
  const float* w1a  = (const float*)d_in[9];
  const float* b1a  = (const float*)d_in[10];
  const float* w2a  = (const float*)d_in[11];
  const float* b2a  = (const float*)d_in[12];
  const float* w1b  = (const float*)d_in[13];
  const float* b1b  = (const float*)d_in[14];
  const float* w2b  = (const float*)d_in[15];
  const float* b2b  = (const float*)d_in[16];
  const float* wq   = (const float*)d_in[17];
  const float* bq   = (const float*)d_in[18];
  const float* wkv  = (const float*)d_in[19];
  const float* bkv  = (const float*)d_in[20];
  const float* wd   = (const float*)d_in[21];
  const float* bd   = (const float*)d_in[22];

  char* ws = (char*)d_ws;
  int* flag = (int*)ws;
  size_t off = 256;
  auto alloc = [&](size_t bytes) {
    void* p = ws + off;
    off += (bytes + 255) & ~(size_t)255;
    return p;
  };
  ushort_t* WT1   = (ushort_t*)alloc(2048ull * 8192 * 2);
  ushort_t* WT2   = (ushort_t*)alloc(2048ull * 8192 * 2);
  ushort_t* WQT   = (ushort_t*)alloc(2048ull * 2048 * 2);
  ushort_t* WKVT  = (ushort_t*)alloc(2048ull * 4096 * 2);
  ushort_t* WDT   = (ushort_t*)alloc(2048ull * 2048 * 2);
  ushort_t* H1    = (ushort_t*)alloc(4096ull * 2048 * 2);
  ushort_t* GELU  = (ushort_t*)alloc(4096ull * 8192 * 2);
  float*    X     = (float*)alloc(4096ull * 2048 * 4);
  ushort_t* QRAW  = (ushort_t*)alloc(4096ull * 2048 * 2);
  ushort_t* PH16  = (ushort_t*)alloc(8192ull * 2048 * 2);
  ushort_t* KVRAW = (ushort_t*)alloc(8192ull * 4096 * 2);
  ushort_t* VT    = PH16;   // alias: past_hidden bf16 dead after kv GEMM
  ushort_t* CTX   = WKVT;   // alias: wkv^T dead after kv GEMM
  unsigned long long* PMASK = (unsigned long long*)GELU;  // alias, see R1 note

  const dim3 tb(32, 8);
  const float SSCALE = 0.088388347648318447f;  // 1/sqrt(128), folded into Q

  detect_mask_k<<<1, 64, 0, stream>>>((const unsigned int*)mask, flag);

  transpose_w<<<dim3(128, 32), 256, 0, stream>>>(w1a, WT1, 2048, 8192);
  transpose_w<<<dim3(32, 128), 256, 0, stream>>>(w2a, WT2, 8192, 2048);
  transpose_w<<<dim3(32, 32), 256, 0, stream>>>(wq, WQT, 2048, 2048);
  transpose_w<<<dim3(64, 32), 256, 0, stream>>>(wkv, WKVT, 2048, 4096);
  transpose_w<<<dim3(32, 32), 256, 0, stream>>>(wd, WDT, 2048, 2048);

  // mlp1 (output REPLACES x)
  ln_kernel<<<4096, 256, 0, stream>>>(x, ln1g, ln1b, H1);
  gemm_w<0><<<1024, 512, 0, stream>>>(H1, WT1, b1a, GELU, 8192, 2048, 2, 0.f);
  gemm_s<2><<<512, 256, 0, stream>>>(GELU, WT2, b2a, nullptr, X, 2048, 8192, 32, 0.f);

  // pack mask now that GELU region is dead
  mask_pack_k<<<1024, 256, 0, stream>>>(mask, flag, PMASK, 262144);

  // attention (l2norm fused into Q/KV GEMM epilogues)
  ln_kernel<<<4096, 256, 0, stream>>>(X, ln2g, ln2b, H1);
  gemm_s<4><<<512, 256, 0, stream>>>(H1, WQT, bq, nullptr, QRAW, 2048, 2048, 32, SSCALE);
  f32_to_bf16_k<<<2048, 256, 0, stream>>>(ph, PH16, 8192 * 2048 / 4);
  gemm_w<4><<<1024, 512, 0, stream>>>(PH16, WKVT, bkv, KVRAW, 4096, 2048, 4, 1.0f);
  vtrans_k<<<dim3(128, 4, 32), tb, 0, stream>>>(KVRAW, VT);
  attn_k<<<512, 512, 0, stream>>>(QRAW, KVRAW, VT, PMASK, CTX);
  gemm_s<3><<<512, 256, 0, stream>>>(CTX, WDT, bd, X, X, 2048, 2048, 32, 0.f);

  // mlp2 (with residual)
  ln_kernel<<<4096, 256, 0, stream>>>(X, ln3g, ln3b, H1);
  transpose_w<<<dim3(128, 32), 256, 0, stream>>>(w1b, WT1, 2048, 8192);
  transpose_w<<<dim3(32, 128), 256, 0, stream>>>(w2b, WT2, 8192, 2048);
  gemm_w<0><<<1024, 512, 0, stream>>>(H1, WT1, b1b, GELU, 8192, 2048, 2, 0.f);
  gemm_s<3><<<512, 256, 0, stream>>>(GELU, WT2, b2b, X, d_out, 2048, 8192, 32, 0.f);
}

// Round 15
// 1255.213 us; speedup vs baseline: 1.0584x; 1.0057x over previous
//
#include <hip/hip_runtime.h>

// ParallelMemoryModule: mlp1 -> memory-attention -> mlp2 on MI355X.
// R14: R13 config (measured best, 1262us) + widened V-transpose (64x64 tile,
// ushort4 global I/O, pad-70 LDS). All GEMM/attn structures unchanged.

typedef unsigned short ushort_t;
typedef __attribute__((ext_vector_type(8))) short bf16x8;
typedef __attribute__((ext_vector_type(4))) float f32x4;

#define DEVI __device__ __forceinline__

DEVI ushort_t f2bf(float f) {
  unsigned int u = __builtin_bit_cast(unsigned int, f);
  u += 0x7FFFu + ((u >> 16) & 1u);
  return (ushort_t)(u >> 16);
}
DEVI float bf2f(ushort_t h) {
  unsigned int u = ((unsigned int)h) << 16;
  return __builtin_bit_cast(float, u);
}

DEVI void load_lds16(const void* g, void* l) {
  __builtin_amdgcn_global_load_lds(
      (__attribute__((address_space(1))) void*)(g),
      (__attribute__((address_space(3))) void*)(l), 16, 0, 0);
}

// ---------------------------------------------------------------- mask dtype
__global__ void detect_mask_k(const unsigned int* __restrict__ m, int* __restrict__ flag) {
  unsigned int v = m[threadIdx.x];
  unsigned long long ok = __ballot(v <= 1u);
  if (threadIdx.x == 0) *flag = (ok == ~0ull) ? 1 : 0;
}

// ---------------------------------------------------------------- mask pack
__global__ __launch_bounds__(256)
void mask_pack_k(const void* __restrict__ maskp, const int* __restrict__ mtype,
                 unsigned long long* __restrict__ out, int nwords) {
  const int mint = *mtype;
  const int lane = threadIdx.x & 63;
  const int wglob = blockIdx.x * 4 + (threadIdx.x >> 6);
  const int nw = gridDim.x * 4;
  const unsigned char* m8 = (const unsigned char*)maskp;
  const int* m32 = (const int*)maskp;
  for (int i = wglob; i < nwords; i += nw) {
    const size_t e = (size_t)i * 64 + lane;
    const bool v = mint ? (m32[e] != 0) : (m8[e] != 0);
    unsigned long long bits = __ballot(v);
    if (lane == 0) out[i] = bits;
  }
}

// ---------------------------------------------------------------- transpose W
__global__ __launch_bounds__(256)
void transpose_w(const float* __restrict__ in, ushort_t* __restrict__ out, int K, int N) {
  __shared__ float t[64][65];
  const int tid = threadIdx.x;
  const int tx = tid & 63, ty = tid >> 6;
  const int n0 = blockIdx.x * 64, k0 = blockIdx.y * 64;
#pragma unroll
  for (int i = 0; i < 16; ++i)
    t[ty + i * 4][tx] = in[(size_t)(k0 + ty + i * 4) * N + n0 + tx];
  __syncthreads();
  const int l32 = tid & 31, nr = tid >> 5;
#pragma unroll
  for (int i = 0; i < 8; ++i) {
    const int n = nr + i * 8;
    ushort2 o;
    o.x = f2bf(t[2 * l32][n]);
    o.y = f2bf(t[2 * l32 + 1][n]);
    *(ushort2*)&out[(size_t)(n0 + n) * K + k0 + 2 * l32] = o;
  }
}

// ---------------------------------------------------------------- f32->bf16
__global__ void f32_to_bf16_k(const float* __restrict__ in, ushort_t* __restrict__ out, int n4) {
  int i = blockIdx.x * blockDim.x + threadIdx.x;
  int stride = gridDim.x * blockDim.x;
  for (; i < n4; i += stride) {
    float4 v = ((const float4*)in)[i];
    ushort4 o;
    o.x = f2bf(v.x); o.y = f2bf(v.y); o.z = f2bf(v.z); o.w = f2bf(v.w);
    ((ushort4*)out)[i] = o;
  }
}

// ---------------------------------------------------------------- layernorm
__global__ __launch_bounds__(256)
void ln_kernel(const float* __restrict__ in, const float* __restrict__ gam,
               const float* __restrict__ bet, ushort_t* __restrict__ out) {
  const int row = blockIdx.x;
  const float* p = in + (size_t)row * 2048;
  const int tid = threadIdx.x;
  float4 v0 = ((const float4*)p)[tid * 2];
  float4 v1 = ((const float4*)p)[tid * 2 + 1];
  float s = v0.x + v0.y + v0.z + v0.w + v1.x + v1.y + v1.z + v1.w;
  float q = v0.x * v0.x + v0.y * v0.y + v0.z * v0.z + v0.w * v0.w +
            v1.x * v1.x + v1.y * v1.y + v1.z * v1.z + v1.w * v1.w;
#pragma unroll
  for (int m = 1; m < 64; m <<= 1) { s += __shfl_xor(s, m); q += __shfl_xor(q, m); }
  __shared__ float red[8];
  const int w = tid >> 6;
  if ((tid & 63) == 0) { red[w] = s; red[4 + w] = q; }
  __syncthreads();
  s = red[0] + red[1] + red[2] + red[3];
  q = red[4] + red[5] + red[6] + red[7];
  const float mean = s * (1.f / 2048.f);
  const float var = q * (1.f / 2048.f) - mean * mean;
  const float rs = rsqrtf(var + 1e-5f);
  float4 g0 = ((const float4*)gam)[tid * 2], g1 = ((const float4*)gam)[tid * 2 + 1];
  float4 b0 = ((const float4*)bet)[tid * 2], b1 = ((const float4*)bet)[tid * 2 + 1];
  ushort4 o0, o1;
  o0.x = f2bf((v0.x - mean) * rs * g0.x + b0.x);
  o0.y = f2bf((v0.y - mean) * rs * g0.y + b0.y);
  o0.z = f2bf((v0.z - mean) * rs * g0.z + b0.z);
  o0.w = f2bf((v0.w - mean) * rs * g0.w + b0.w);
  o1.x = f2bf((v1.x - mean) * rs * g1.x + b1.x);
  o1.y = f2bf((v1.y - mean) * rs * g1.y + b1.y);
  o1.z = f2bf((v1.z - mean) * rs * g1.z + b1.z);
  o1.w = f2bf((v1.w - mean) * rs * g1.w + b1.w);
  ushort4* ob = (ushort4*)(out + (size_t)row * 2048);
  ob[tid * 2] = o0;
  ob[tid * 2 + 1] = o1;
}

// ---------------------------------------------------------------- V transpose
// kv bf16 [8192 rows][4096], V at col h*256+128+d -> vt[(b*16+h)*128+d][m].
// 64(m) x 64(d) tile, 256 threads, ushort4 global I/O both phases.
__global__ __launch_bounds__(256)
void vtrans64(const ushort_t* __restrict__ kv, ushort_t* __restrict__ vt) {
  __shared__ ushort_t t[64][70];  // stride 70 (~3 banks) -> <=2-way conflicts
  const int tid = threadIdx.x;
  const int m0 = blockIdx.x * 64, d0 = blockIdx.y * 64, bh = blockIdx.z;
  const int b = bh >> 4, h = bh & 15;
  const int dq = (tid & 15) * 4;
  const int mr = tid >> 4;
#pragma unroll
  for (int i = 0; i < 4; ++i) {
    const int m = mr + i * 16;
    const ushort_t* src =
        kv + ((size_t)(m0 + m) * 2 + b) * 4096 + h * 256 + 128 + d0 + dq;
    ushort4 v = *(const ushort4*)src;
    t[m][dq] = v.x; t[m][dq + 1] = v.y; t[m][dq + 2] = v.z; t[m][dq + 3] = v.w;
  }
  __syncthreads();
  const int mq = (tid & 15) * 4;
  const int dr = tid >> 4;
#pragma unroll
  for (int i = 0; i < 4; ++i) {
    const int d = dr + i * 16;
    ushort4 o;
    o.x = t[mq][d]; o.y = t[mq + 1][d]; o.z = t[mq + 2][d]; o.w = t[mq + 3][d];
    *(ushort4*)&vt[((size_t)bh * 128 + d0 + d) * 4096 + m0 + mq] = o;
  }
}

// ---------------------------------------------------------------- GEMM 128^2
// m97-class (PROVEN): 128x128, BK=64, 4 waves, single-buf 32KB, 2-barrier,
// 3 blocks/CU (124 regs/thread: VGPR 60 + AGPR 64).
// EPI: 0 bias+gelu->bf16 ; 2 bias->f32 ; 3 Xres+acc+bias->f32 ;
//      4 l2norm(row over 128 tile cols)*nscale -> bf16
template <int EPI>
__global__ __launch_bounds__(256, 3)
void gemm_s(const ushort_t* __restrict__ A, const ushort_t* __restrict__ Bt,
            const float* __restrict__ bias, const float* __restrict__ Xres,
            void* __restrict__ Out, int N, int K, int GM, float nscale) {
  __shared__ ushort_t lA[128 * 64];
  __shared__ ushort_t lB[128 * 64];

  const int tid = threadIdx.x;
  const int lane = tid & 63;
  const int w = tid >> 6;
  const int l15 = lane & 15, lhi = lane >> 4;
  const int wr = w >> 1, wc = w & 1;

  const int nwg = gridDim.x;
  const int cpx = nwg >> 3;
  const int swz = (blockIdx.x & 7) * cpx + (blockIdx.x >> 3);
  const int tm = swz % GM, tn = swz / GM;

  size_t aSrc[4], bSrc[4];
#pragma unroll
  for (int i = 0; i < 4; ++i) {
    const int ch = i * 256 + tid;
    const int row = ch >> 3;
    const int colb = ((ch & 7) * 16) ^ ((row & 7) << 4);
    aSrc[i] = (size_t)(tm * 128 + row) * K + (colb >> 1);
    bSrc[i] = (size_t)(tn * 128 + row) * K + (colb >> 1);
  }

  f32x4 acc[4][4] = {};

  const int KT = K >> 6;
  for (int kt = 0; kt < KT; ++kt) {
    const int k0 = kt << 6;
#pragma unroll
    for (int i = 0; i < 4; ++i) {
      load_lds16(A + aSrc[i] + k0, (char*)lA + (i * 256 + tid) * 16);
      load_lds16(Bt + bSrc[i] + k0, (char*)lB + (i * 256 + tid) * 16);
    }
    __syncthreads();
#pragma unroll
    for (int kk = 0; kk < 2; ++kk) {
      const int kb = kk * 64 + lhi * 16;
      bf16x8 bfr[4], af[4];
#pragma unroll
      for (int nf = 0; nf < 4; ++nf) {
        const int rb = wc * 64 + nf * 16 + l15;
        bfr[nf] = *(const bf16x8*)((const char*)lB + rb * 128 + (kb ^ ((rb & 7) << 4)));
      }
#pragma unroll
      for (int mf = 0; mf < 4; ++mf) {
        const int ra = wr * 64 + mf * 16 + l15;
        af[mf] = *(const bf16x8*)((const char*)lA + ra * 128 + (kb ^ ((ra & 7) << 4)));
      }
#pragma unroll
      for (int mf = 0; mf < 4; ++mf)
#pragma unroll
        for (int nf = 0; nf < 4; ++nf)
          acc[mf][nf] = __builtin_amdgcn_mfma_f32_16x16x32_bf16(af[mf], bfr[nf], acc[mf][nf], 0, 0, 0);
    }
    __syncthreads();
  }

  const int row0 = tm * 128 + wr * 64;
  const int col0 = tn * 128 + wc * 64;
  float bj[4];
#pragma unroll
  for (int nf = 0; nf < 4; ++nf) bj[nf] = bias[col0 + nf * 16 + l15];

  float inv_n[4][4];
  if constexpr (EPI == 4) {
    float part[4][4];
#pragma unroll
    for (int mf = 0; mf < 4; ++mf)
#pragma unroll
      for (int r = 0; r < 4; ++r) {
        float p = 0.f;
#pragma unroll
        for (int nf = 0; nf < 4; ++nf) {
          const float v = acc[mf][nf][r] + bj[nf];
          p += v * v;
        }
        part[mf][r] = p;
      }
#pragma unroll
    for (int ms = 1; ms < 16; ms <<= 1)
#pragma unroll
      for (int mf = 0; mf < 4; ++mf)
#pragma unroll
        for (int r = 0; r < 4; ++r) part[mf][r] += __shfl_xor(part[mf][r], ms);
    float* sq = (float*)lA;
    if (l15 == 0) {
#pragma unroll
      for (int mf = 0; mf < 4; ++mf)
#pragma unroll
        for (int r = 0; r < 4; ++r)
          sq[wc * 128 + wr * 64 + mf * 16 + lhi * 4 + r] = part[mf][r];
    }
    __syncthreads();
#pragma unroll
    for (int mf = 0; mf < 4; ++mf)
#pragma unroll
      for (int r = 0; r < 4; ++r) {
        const int idx = wr * 64 + mf * 16 + lhi * 4 + r;
        const float tot = sq[idx] + sq[128 + idx];
        inv_n[mf][r] = nscale / fmaxf(sqrtf(tot), 1e-12f);
      }
  }

#pragma unroll
  for (int mf = 0; mf < 4; ++mf) {
#pragma unroll
    for (int nf = 0; nf < 4; ++nf) {
      const int col = col0 + nf * 16 + l15;
#pragma unroll
      for (int r = 0; r < 4; ++r) {
        const int row = row0 + mf * 16 + lhi * 4 + r;
        const size_t idx = (size_t)row * N + col;
        float v = acc[mf][nf][r] + bj[nf];
        if constexpr (EPI == 0) {
          v = 0.5f * v * (1.f + erff(v * 0.70710678118654752f));
          ((ushort_t*)Out)[idx] = f2bf(v);
        } else if constexpr (EPI == 2) {
          ((float*)Out)[idx] = v;
        } else if constexpr (EPI == 3) {
          ((float*)Out)[idx] = Xres[idx] + v;
        } else {
          ((ushort_t*)Out)[idx] = f2bf(v * inv_n[mf][r]);
        }
      }
    }
  }
}

// ---------------------------------------------------------------- GEMM 128x256
// (R11 proven): BK=64, single-buf 48KB, 8 waves, (512,4) -> 2 blocks/CU.
// 2D XCD patch mapping (R13; wall-clock neutral, FETCH -30%).
// EPI: 0 bias+gelu->bf16 ; 4 per-128-col-segment l2norm*nscale -> bf16
template <int EPI>
__global__ __launch_bounds__(512, 4)
void gemm_w(const ushort_t* __restrict__ A, const ushort_t* __restrict__ Bt,
            const float* __restrict__ bias, void* __restrict__ Out,
            int N, int K, int GX, float nscale) {
  __shared__ ushort_t lA[128 * 64];
  __shared__ ushort_t lB[256 * 64];

  const int tid = threadIdx.x;
  const int lane = tid & 63;
  const int w = tid >> 6;
  const int l15 = lane & 15, lhi = lane >> 4;
  const int wr = w >> 2, wc = w & 3;

  const int xcd = blockIdx.x & 7;
  const int c = blockIdx.x >> 3;
  const int tm = (xcd % GX) * 16 + (c & 15);
  const int tn = (xcd / GX) * 8 + (c >> 4);

  size_t aSrc[2], bSrc[4];
#pragma unroll
  for (int i = 0; i < 2; ++i) {
    const int ch = i * 512 + tid;
    const int row = ch >> 3;
    const int colb = ((ch & 7) * 16) ^ ((row & 7) << 4);
    aSrc[i] = (size_t)(tm * 128 + row) * K + (colb >> 1);
  }
#pragma unroll
  for (int i = 0; i < 4; ++i) {
    const int ch = i * 512 + tid;
    const int row = ch >> 3;
    const int colb = ((ch & 7) * 16) ^ ((row & 7) << 4);
    bSrc[i] = (size_t)(tn * 256 + row) * K + (colb >> 1);
  }

  f32x4 acc[4][4] = {};

  const int KT = K >> 6;
  for (int kt = 0; kt < KT; ++kt) {
    const int k0 = kt << 6;
#pragma unroll
    for (int i = 0; i < 2; ++i)
      load_lds16(A + aSrc[i] + k0, (char*)lA + (i * 512 + tid) * 16);
#pragma unroll
    for (int i = 0; i < 4; ++i)
      load_lds16(Bt + bSrc[i] + k0, (char*)lB + (i * 512 + tid) * 16);
    __syncthreads();
#pragma unroll
    for (int kk = 0; kk < 2; ++kk) {
      const int kb = kk * 64 + lhi * 16;
      bf16x8 bfr[4], af[4];
#pragma unroll
      for (int nf = 0; nf < 4; ++nf) {
        const int rb = wc * 64 + nf * 16 + l15;
        bfr[nf] = *(const bf16x8*)((const char*)lB + rb * 128 + (kb ^ ((rb & 7) << 4)));
      }
#pragma unroll
      for (int mf = 0; mf < 4; ++mf) {
        const int ra = wr * 64 + mf * 16 + l15;
        af[mf] = *(const bf16x8*)((const char*)lA + ra * 128 + (kb ^ ((ra & 7) << 4)));
      }
#pragma unroll
      for (int mf = 0; mf < 4; ++mf)
#pragma unroll
        for (int nf = 0; nf < 4; ++nf)
          acc[mf][nf] = __builtin_amdgcn_mfma_f32_16x16x32_bf16(af[mf], bfr[nf], acc[mf][nf], 0, 0, 0);
    }
    __syncthreads();
  }

  const int row0 = tm * 128 + wr * 64;
  const int col0 = tn * 256 + wc * 64;
  float bj[4];
#pragma unroll
  for (int nf = 0; nf < 4; ++nf) bj[nf] = bias[col0 + nf * 16 + l15];

  float inv_n[4][4];
  if constexpr (EPI == 4) {
    float part[4][4];
#pragma unroll
    for (int mf = 0; mf < 4; ++mf)
#pragma unroll
      for (int r = 0; r < 4; ++r) {
        float p = 0.f;
#pragma unroll
        for (int nf = 0; nf < 4; ++nf) {
          const float v = acc[mf][nf][r] + bj[nf];
          p += v * v;
        }
        part[mf][r] = p;
      }
#pragma unroll
    for (int ms = 1; ms < 16; ms <<= 1)
#pragma unroll
      for (int mf = 0; mf < 4; ++mf)
#pragma unroll
        for (int r = 0; r < 4; ++r) part[mf][r] += __shfl_xor(part[mf][r], ms);
    float* sq = (float*)lA;  // [4 wc][128 rows]
    if (l15 == 0) {
#pragma unroll
      for (int mf = 0; mf < 4; ++mf)
#pragma unroll
        for (int r = 0; r < 4; ++r)
          sq[wc * 128 + wr * 64 + mf * 16 + lhi * 4 + r] = part[mf][r];
    }
    __syncthreads();
#pragma unroll
    for (int mf = 0; mf < 4; ++mf)
#pragma unroll
      for (int r = 0; r < 4; ++r) {
        const int idx = wr * 64 + mf * 16 + lhi * 4 + r;
        const float tot = sq[wc * 128 + idx] + sq[(wc ^ 1) * 128 + idx];
        inv_n[mf][r] = nscale / fmaxf(sqrtf(tot), 1e-12f);
      }
  }

#pragma unroll
  for (int mf = 0; mf < 4; ++mf) {
#pragma unroll
    for (int nf = 0; nf < 4; ++nf) {
      const int col = col0 + nf * 16 + l15;
#pragma unroll
      for (int r = 0; r < 4; ++r) {
        const int row = row0 + mf * 16 + lhi * 4 + r;
        const size_t idx = (size_t)row * N + col;
        float v = acc[mf][nf][r] + bj[nf];
        if constexpr (EPI == 0) {
          v = 0.5f * v * (1.f + erff(v * 0.70710678118654752f));
          ((ushort_t*)Out)[idx] = f2bf(v);
        } else {
          ((ushort_t*)Out)[idx] = f2bf(v * inv_n[mf][r]);
        }
      }
    }
  }
}

// ---------------------------------------------------------------- attention
// (unchanged from R8)
__global__ __launch_bounds__(512, 4)
void attn_k(const ushort_t* __restrict__ Q, const ushort_t* __restrict__ KV,
            const ushort_t* __restrict__ VT,
            const unsigned long long* __restrict__ PM,
            ushort_t* __restrict__ CTX) {
  __shared__ ushort_t lk[2][64 * 128];
  __shared__ ushort_t lvt[2][128 * 64];
  __shared__ ushort_t lp[8][16 * 64];

  const int tid = threadIdx.x, lane = tid & 63, w = tid >> 6;
  const int l15 = lane & 15, lhi = lane >> 4;
  const int wid = ((blockIdx.x & 7) << 6) + (blockIdx.x >> 3);
  const int qt = wid & 15, pair = wid >> 4;
  const int b = pair >> 4, h = pair & 15;

  size_t kSrc[2], vSrc[2];
  int kDst[2], vDst[2];
#pragma unroll
  for (int i = 0; i < 2; ++i) {
    const int ch = (i * 8 + w) * 64 + lane;
    {
      const int row = ch >> 4;
      const int cb = ((ch & 15) * 16) ^ ((row & 7) << 4);
      kSrc[i] = ((size_t)row * 2 + b) * 4096 + h * 256 + (cb >> 1);
      kDst[i] = (i * 8 + w) * 1024;
    }
    {
      const int row = ch >> 3;
      const int cb = ((ch & 7) * 16) ^ ((row & 7) << 4);
      vSrc[i] = (size_t)pair * 128 * 4096 + (size_t)row * 4096 + (cb >> 1);
      vDst[i] = (i * 8 + w) * 1024;
    }
  }

  bf16x8 aq[4];
  {
    const ushort_t* qbase =
        Q + ((size_t)(qt * 128 + w * 16 + l15) * 2 + b) * 2048 + h * 128 + lhi * 8;
#pragma unroll
    for (int kk = 0; kk < 4; ++kk) aq[kk] = *(const bf16x8*)(qbase + kk * 32);
  }

  float l_acc[4] = {0.f, 0.f, 0.f, 0.f};
  f32x4 acc_o[8] = {};
  const unsigned long long* mrow =
      PM + (size_t)(b * 2048 + qt * 128 + w * 16 + lhi * 4) * 64;
  const int l15p16 = l15 + 16;

#pragma unroll
  for (int i = 0; i < 2; ++i) {
    load_lds16(KV + kSrc[i], (char*)lk[0] + kDst[i]);
    load_lds16(VT + vSrc[i], (char*)lvt[0] + vDst[i]);
  }
  __syncthreads();

  int cur = 0;
  for (int t = 0; t < 64; ++t) {
    if (t < 63) {
      const size_t kAdd = (size_t)(t + 1) * 64 * 8192;
      const int vAdd = (t + 1) * 64;
#pragma unroll
      for (int i = 0; i < 2; ++i) {
        load_lds16(KV + kSrc[i] + kAdd, (char*)lk[cur ^ 1] + kDst[i]);
        load_lds16(VT + vSrc[i] + vAdd, (char*)lvt[cur ^ 1] + vDst[i]);
      }
    }
    unsigned long long mw[4];
#pragma unroll
    for (int r = 0; r < 4; ++r) mw[r] = mrow[r * 64 + t];

    f32x4 sa[4] = {};
#pragma unroll
    for (int kk = 0; kk < 4; ++kk) {
#pragma unroll
      for (int j = 0; j < 4; ++j) {
        const int krow = j * 16 + l15;
        const int bcb = (kk * 64 + lhi * 16) ^ ((krow & 7) << 4);
        bf16x8 bk = *(const bf16x8*)((const char*)lk[cur] + krow * 256 + bcb);
        sa[j] = __builtin_amdgcn_mfma_f32_16x16x32_bf16(aq[kk], bk, sa[j], 0, 0, 0);
      }
    }

#pragma unroll
    for (int r = 0; r < 4; ++r) {
      const unsigned int mlo = (unsigned int)mw[r];
      const unsigned int mhi = (unsigned int)(mw[r] >> 32);
#pragma unroll
      for (int j = 0; j < 4; ++j) {
        const unsigned int sel = (j < 2) ? mlo : mhi;
        const int sh = (j & 1) ? l15p16 : l15;
        const bool mk = (sel >> sh) & 1u;
        const float p = __expf(sa[j][r]);
        const float pv = mk ? 0.f : p;
        sa[j][r] = pv;
        l_acc[r] += pv;
      }
    }

#pragma unroll
    for (int r = 0; r < 4; ++r) {
      unsigned int pk0, pk1;
      asm("v_cvt_pk_bf16_f32 %0, %1, %2" : "=v"(pk0) : "v"(sa[0][r]), "v"(sa[1][r]));
      asm("v_cvt_pk_bf16_f32 %0, %1, %2" : "=v"(pk1) : "v"(sa[2][r]), "v"(sa[3][r]));
      const int prow = lhi * 4 + r;
      char* base = (char*)lp[w] + prow * 128;
      const int swz = (prow & 7) << 4;
      *(ushort_t*)(base + ((l15 * 2) ^ swz)) = (ushort_t)pk0;
      *(ushort_t*)(base + (((16 + l15) * 2) ^ swz)) = (ushort_t)(pk0 >> 16);
      *(ushort_t*)(base + (((32 + l15) * 2) ^ swz)) = (ushort_t)pk1;
      *(ushort_t*)(base + (((48 + l15) * 2) ^ swz)) = (ushort_t)(pk1 >> 16);
    }

#pragma unroll
    for (int ks = 0; ks < 2; ++ks) {
      const int acb2 = (ks * 64 + lhi * 16) ^ ((l15 & 7) << 4);
      bf16x8 ap = *(const bf16x8*)((const char*)lp[w] + l15 * 128 + acb2);
#pragma unroll
      for (int d = 0; d < 8; ++d) {
        const int vrow = d * 16 + l15;
        const int vcb = (ks * 64 + lhi * 16) ^ ((vrow & 7) << 4);
        bf16x8 bv = *(const bf16x8*)((const char*)lvt[cur] + vrow * 128 + vcb);
        acc_o[d] = __builtin_amdgcn_mfma_f32_16x16x32_bf16(ap, bv, acc_o[d], 0, 0, 0);
      }
    }
    __syncthreads();
    cur ^= 1;
  }

#pragma unroll
  for (int ms = 1; ms < 16; ms <<= 1)
#pragma unroll
    for (int r = 0; r < 4; ++r) l_acc[r] += __shfl_xor(l_acc[r], ms);

#pragma unroll
  for (int r = 0; r < 4; ++r) {
    const float inv = 1.f / fmaxf(l_acc[r], 1e-20f);
    const size_t orow = ((size_t)(qt * 128 + w * 16 + lhi * 4 + r) * 2 + b) * 2048 + h * 128;
#pragma unroll
    for (int d = 0; d < 8; ++d)
      CTX[orow + d * 16 + l15] = f2bf(acc_o[d][r] * inv);
  }
}

// ---------------------------------------------------------------- launch
extern "C" void kernel_launch(void* const* d_in, const int* in_sizes, int n_in,
                              void* d_out, int out_size, void* d_ws, size_t ws_size,
                              hipStream_t stream) {
  (void)in_sizes; (void)n_in; (void)out_size; (void)ws_size;
  const float* x    = (const float*)d_in[0];
  const float* ph   = (const float*)d_in[1];
  const void*  mask = d_in[2];
  const float* ln1g = (const float*)d_in[3];
  const float* ln1b = (const float*)d_in[4];
  const float* ln2g = (const float*)d_in[5];
  const float* ln2b = (const float*)d_in[6];
  const float* ln3g = (const float*)d_in[7];
  const float* ln3b = (const float*)d_in[8];
  const float* w1a  = (const float*)d_in[9];
  const float* b1a  = (const float*)d_in[10];
  const float* w2a  = (const float*)d_in[11];
  const float* b2a  = (const float*)d_in[12];
  const float* w1b  = (const float*)d_in[13];
  const float* b1b  = (const float*)d_in[14];
  const float* w2b  = (const float*)d_in[15];
  const float* b2b  = (const float*)d_in[16];
  const float* wq   = (const float*)d_in[17];
  const float* bq   = (const float*)d_in[18];
  const float* wkv  = (const float*)d_in[19];
  const float* bkv  = (const float*)d_in[20];
  const float* wd   = (const float*)d_in[21];
  const float* bd   = (const float*)d_in[22];

  char* ws = (char*)d_ws;
  int* flag = (int*)ws;
  size_t off = 256;
  auto alloc = [&](size_t bytes) {
    void* p = ws + off;
    off += (bytes + 255) & ~(size_t)255;
    return p;
  };
  ushort_t* WT1   = (ushort_t*)alloc(2048ull * 8192 * 2);
  ushort_t* WT2   = (ushort_t*)alloc(2048ull * 8192 * 2);
  ushort_t* WQT   = (ushort_t*)alloc(2048ull * 2048 * 2);
  ushort_t* WKVT  = (ushort_t*)alloc(2048ull * 4096 * 2);
  ushort_t* WDT   = (ushort_t*)alloc(2048ull * 2048 * 2);
  ushort_t* H1    = (ushort_t*)alloc(4096ull * 2048 * 2);
  ushort_t* GELU  = (ushort_t*)alloc(4096ull * 8192 * 2);
  float*    X     = (float*)alloc(4096ull * 2048 * 4);
  ushort_t* QRAW  = (ushort_t*)alloc(4096ull * 2048 * 2);
  ushort_t* PH16  = (ushort_t*)alloc(8192ull * 2048 * 2);
  ushort_t* KVRAW = (ushort_t*)alloc(8192ull * 4096 * 2);
  ushort_t* VT    = PH16;   // alias: past_hidden bf16 dead after kv GEMM
  ushort_t* CTX   = WKVT;   // alias: wkv^T dead after kv GEMM
  unsigned long long* PMASK = (unsigned long long*)GELU;  // alias, see R1 note

  const float SSCALE = 0.088388347648318447f;  // 1/sqrt(128), folded into Q

  detect_mask_k<<<1, 64, 0, stream>>>((const unsigned int*)mask, flag);

  transpose_w<<<dim3(128, 32), 256, 0, stream>>>(w1a, WT1, 2048, 8192);
  transpose_w<<<dim3(32, 128), 256, 0, stream>>>(w2a, WT2, 8192, 2048);
  transpose_w<<<dim3(32, 32), 256, 0, stream>>>(wq, WQT, 2048, 2048);
  transpose_w<<<dim3(64, 32), 256, 0, stream>>>(wkv, WKVT, 2048, 4096);
  transpose_w<<<dim3(32, 32), 256, 0, stream>>>(wd, WDT, 2048, 2048);

  // mlp1 (output REPLACES x)
  ln_kernel<<<4096, 256, 0, stream>>>(x, ln1g, ln1b, H1);
  gemm_w<0><<<1024, 512, 0, stream>>>(H1, WT1, b1a, GELU, 8192, 2048, 2, 0.f);
  gemm_s<2><<<512, 256, 0, stream>>>(GELU, WT2, b2a, nullptr, X, 2048, 8192, 32, 0.f);

  // pack mask now that GELU region is dead
  mask_pack_k<<<1024, 256, 0, stream>>>(mask, flag, PMASK, 262144);

  // attention (l2norm fused into Q/KV GEMM epilogues)
  ln_kernel<<<4096, 256, 0, stream>>>(X, ln2g, ln2b, H1);
  gemm_s<4><<<512, 256, 0, stream>>>(H1, WQT, bq, nullptr, QRAW, 2048, 2048, 32, SSCALE);
  f32_to_bf16_k<<<2048, 256, 0, stream>>>(ph, PH16, 8192 * 2048 / 4);
  gemm_w<4><<<1024, 512, 0, stream>>>(PH16, WKVT, bkv, KVRAW, 4096, 2048, 4, 1.0f);
  vtrans64<<<dim3(64, 2, 32), 256, 0, stream>>>(KVRAW, VT);
  attn_k<<<512, 512, 0, stream>>>(QRAW, KVRAW, VT, PMASK, CTX);
  gemm_s<3><<<512, 256, 0, stream>>>(CTX, WDT, bd, X, X, 2048, 2048, 32, 0.f);

  // mlp2 (with residual)
  ln_kernel<<<4096, 256, 0, stream>>>(X, ln3g, ln3b, H1);
  transpose_w<<<dim3(128, 32), 256, 0, stream>>>(w1b, WT1, 2048, 8192);
  transpose_w<<<dim3(32, 128), 256, 0, stream>>>(w2b, WT2, 8192, 2048);
  gemm_w<0><<<1024, 512, 0, stream>>>(H1, WT1, b1b, GELU, 8192, 2048, 2, 0.f);
  gemm_s<3><<<512, 256, 0, stream>>>(GELU, WT2, b2b, X, d_out, 2048, 8192, 32, 0.f);
}